// Round 5
// baseline (43604.871 us; speedup 1.0000x reference)
//
#include <hip/hip_runtime.h>

// ---------------------------------------------------------------------------
// NS_Flashed_TotalSimRetina — GLM retina simulation, round 10.
// Diagnosis refined from rounds 6-9 (all VGPR=84): for a 600-thread wg the
// hard VGPR cap is 512/ceil(10/4) = 168; the live set peaked at ~210
// (acc[100] + ~25 scalars + ~100 regs of scheduler-hoisted in-flight weight
// loads), so RA split the budget 84 VGPR + 84 AGPR (gfx950 spill-to-AGPR)
// and pushed ~40 slots to scratch (measured: WRITE_SIZE ~1GB = 34-50
// f32/thread/step). Budget attrs can't fix pressure.
// Fix (pressure control, compile-time):
//   - every 25-block weight loop is chunked 5x5 with
//     __builtin_amdgcn_sched_barrier(0) fences -> in-flight <= 5 uint4
//     (20 VGPRs) instead of ~100.
//   - p-loop fully unrolled -> selpv[p]/sp[p] statically indexed (no
//     rule-#20 scratch arrays).
//   Peak ~= 130 persistent + 20 in-flight ~= 150 < 168.
// Everything else (per-batch wg, LDS spike exchange, 4-cell-interleaved
// single-base weight layout) unchanged from round 9.
// ---------------------------------------------------------------------------

#define NC     600
#define NPIX   4096
#define NBF    100
#define MC     20
#define NB     500
#define NBI    100
#define NBATCH 32
#define NSTEP  400

typedef unsigned int u32;
typedef _Float16 f16x2 __attribute__((ext_vector_type(2)));

__device__ __forceinline__ float dot2(u32 a, u32 b, float acc) {
  return __builtin_amdgcn_fdot2(__builtin_bit_cast(f16x2, a),
                                __builtin_bit_cast(f16x2, b), acc, false);
}
__device__ __forceinline__ u32 pkrtz(float a, float b) {
  return __builtin_bit_cast(u32, __builtin_amdgcn_cvt_pkrtz(a, b));
}

// --- stim_applied[b][c] = sum_p stim[b][p] * spat[c][p] ---------------------
__global__ void applied_kernel(const float* __restrict__ stim,
                               const float* __restrict__ spat,
                               float* __restrict__ applied) {
  const int c = blockIdx.x, b = blockIdx.y;
  __shared__ float red[256];
  float a = 0.f;
  for (int p = threadIdx.x; p < NPIX; p += 256)
    a += stim[b * NPIX + p] * spat[c * NPIX + p];
  red[threadIdx.x] = a;
  __syncthreads();
  for (int s = 128; s > 0; s >>= 1) {
    if (threadIdx.x < s) red[threadIdx.x] += red[threadIdx.x + s];
    __syncthreads();
  }
  if (threadIdx.x == 0) applied[b * NC + c] = red[0];
}

// --- convT[t][c] = sum_f stc[t+f] * tcf[c][f] ------------------------------
__global__ void conv_kernel(const float* __restrict__ stc,
                            const float* __restrict__ tcf,
                            float* __restrict__ convT) {
  int idx = blockIdx.x * 256 + threadIdx.x;
  if (idx >= NSTEP * NC) return;
  int t = idx / NC, c = idx - t * NC;
  float a = 0.f;
  for (int f = 0; f < NBF; ++f)
    a += stc[t + f] * tcf[c * NBF + f];
  convT[idx] = a;
}

// --- packed, time-reversed, edge-paired, 4-CELL-INTERLEAVED filter table ---
// Logical per-cell stream: tap-block k = p*25 + (i>>2) for pair p<10,
// k = 250 + (i>>2) for feedback; element j = i&3 within the uint4.
// Stored at uint4 index ((c>>2)*275 + k)*4 + (c&3):
//   - lane c's 275 blocks are at ONE base + offsets k*64B (imm-foldable)
//   - lane quads (4 consecutive c) read contiguous 64B lines.
__global__ void pack_kernel(const float* __restrict__ cf,
                            const float* __restrict__ ff,
                            u32* __restrict__ wPT) {
  int idx = blockIdx.x * 256 + threadIdx.x;
  if (idx >= NC * 1100) return;
  int c = idx / 1100;
  int r = idx - c * 1100;
  int p = r / 100;
  int i = r - p * 100;
  int f = 99 - i;
  float lo, hi;
  if (p < 10) {
    lo = cf[(c * MC + 2 * p) * NBF + f];
    hi = cf[(c * MC + 2 * p + 1) * NBF + f];
  } else {
    lo = ff[c * NBF + f];
    hi = 0.f;
  }
  const int k = p * 25 + (i >> 2);
  wPT[((((c >> 2) * 275 + k) * 4 + (c & 3)) << 2) + (i & 3)] = pkrtz(lo, hi);
}

// --- packed source pairs, transposed: selpT[p][c] = src0 | (src1 << 16) ----
__global__ void selp_kernel(const int* __restrict__ sel, u32* __restrict__ selpT) {
  int idx = blockIdx.x * 256 + threadIdx.x;
  if (idx >= NC * 10) return;
  int c = idx / 10, p = idx - c * 10;
  u32 s0 = (u32)sel[c * MC + 2 * p];
  u32 s1 = (u32)sel[c * MC + 2 * p + 1];
  selpT[p * NC + c] = s0 | (s1 << 16);
}

// --- initT2[b][tau][c] = init[b][c][tau]  (coalesced per-step reads) -------
__global__ void initT2_kernel(const float* __restrict__ init,
                              float* __restrict__ initT2) {
  int idx = blockIdx.x * 256 + threadIdx.x;
  if (idx >= NBATCH * NBI * NC) return;
  int c = idx % NC;
  int r = idx / NC;
  int tau = r % NBI;
  int b = r / NBI;
  initT2[idx] = init[(b * NC + c) * NBI + tau];
}

// --- copy initial spikes into output (first 100 bins of each row) ----------
__global__ void copy_init_kernel(const float4* __restrict__ init,
                                 float4* __restrict__ out) {
  int idx = blockIdx.x * 256 + threadIdx.x;
  if (idx >= NBATCH * NC * (NBI / 4)) return;
  int k4 = idx % (NBI / 4);
  int bc = idx / (NBI / 4);
  out[bc * (NB / 4) + k4] = init[idx];
}

// one 5-load / 20-dot2 chunk, fenced so the scheduler can't pile up loads
#define CHUNK(K0, SPV)                                                       \
  {                                                                          \
    uint4 w0 = wc[(K0 + 0) * 4];                                             \
    uint4 w1 = wc[(K0 + 1) * 4];                                             \
    uint4 w2 = wc[(K0 + 2) * 4];                                             \
    uint4 w3 = wc[(K0 + 3) * 4];                                             \
    uint4 w4 = wc[(K0 + 4) * 4];                                             \
    __builtin_amdgcn_sched_barrier(0);                                       \
    acc[(K0 + 0) % 25 * 4 + 0 + 0 * 0] = acc[(K0 + 0) % 25 * 4];             \
    (void)0;                                                                 \
    {                                                                        \
      const int i0 = ((K0) % 25) * 4;                                        \
      acc[i0 + 0]  = dot2(w0.x, SPV, acc[i0 + 0]);                           \
      acc[i0 + 1]  = dot2(w0.y, SPV, acc[i0 + 1]);                           \
      acc[i0 + 2]  = dot2(w0.z, SPV, acc[i0 + 2]);                           \
      acc[i0 + 3]  = dot2(w0.w, SPV, acc[i0 + 3]);                           \
      acc[i0 + 4]  = dot2(w1.x, SPV, acc[i0 + 4]);                           \
      acc[i0 + 5]  = dot2(w1.y, SPV, acc[i0 + 5]);                           \
      acc[i0 + 6]  = dot2(w1.z, SPV, acc[i0 + 6]);                           \
      acc[i0 + 7]  = dot2(w1.w, SPV, acc[i0 + 7]);                           \
      acc[i0 + 8]  = dot2(w2.x, SPV, acc[i0 + 8]);                           \
      acc[i0 + 9]  = dot2(w2.y, SPV, acc[i0 + 9]);                           \
      acc[i0 + 10] = dot2(w2.z, SPV, acc[i0 + 10]);                          \
      acc[i0 + 11] = dot2(w2.w, SPV, acc[i0 + 11]);                          \
      acc[i0 + 12] = dot2(w3.x, SPV, acc[i0 + 12]);                          \
      acc[i0 + 13] = dot2(w3.y, SPV, acc[i0 + 13]);                          \
      acc[i0 + 14] = dot2(w3.z, SPV, acc[i0 + 14]);                          \
      acc[i0 + 15] = dot2(w3.w, SPV, acc[i0 + 15]);                          \
      acc[i0 + 16] = dot2(w4.x, SPV, acc[i0 + 16]);                          \
      acc[i0 + 17] = dot2(w4.y, SPV, acc[i0 + 17]);                          \
      acc[i0 + 18] = dot2(w4.z, SPV, acc[i0 + 18]);                          \
      acc[i0 + 19] = dot2(w4.w, SPV, acc[i0 + 19]);                          \
    }                                                                        \
    __builtin_amdgcn_sched_barrier(0);                                       \
  }

// --- the recurrence: one workgroup per batch, LDS spike exchange -----------
__global__ __attribute__((amdgpu_flat_work_group_size(600, 600)))
void sim_kernel(
    const float* __restrict__ bias, const float* __restrict__ applied,
    const float* __restrict__ convT, const uint4* __restrict__ wp,
    const u32* __restrict__ selpT, const float* __restrict__ initT2,
    float* __restrict__ out) {
  const int c = threadIdx.x;     // cell, 0..599
  const int b = blockIdx.x;      // batch, 0..31

  __shared__ float spk[2][NC];   // double-buffered current-step spikes

  float acc[NBF];
#pragma unroll
  for (int i = 0; i < NBF; ++i) acc[i] = 0.f;

  u32 selpv[10];
#pragma unroll
  for (int p = 0; p < 10; ++p) selpv[p] = selpT[p * NC + c];  // coalesced

  const float biasv = bias[c];
  const float appv  = applied[b * NC + c];
  const float* ib2  = initT2 + (size_t)b * NBI * NC;
  float* outS = out + (size_t)(b * NC + c) * NB + NBI;
  float* outG = out + (size_t)NBATCH * NC * NB + (size_t)(b * NC + c) * NSTEP;

  // single per-lane weight base; tap-block k lives at wc[k*4] (offset k*64B)
  const uint4* wc = wp + ((c >> 2) * 1100 + (c & 3));

#pragma unroll 1
  for (int tau = 0; tau < NB; ++tau) {
    const int t  = tau - NBI;
    const int pb = tau & 1;
    float sv;
    if (t >= 0) {
      float g = biasv + appv * convT[t * NC + c] + acc[0];
      sv = 1.f / (1.f + __expf(-g));
      outS[t] = sv;
      outG[t] = g;
    } else {
      sv = ib2[tau * NC + c];
    }
    spk[pb][c] = sv;

    // rotate: acc[i] <- contributions to step (tau+1)+i
#pragma unroll
    for (int i = 0; i < NBF - 1; ++i) acc[i] = acc[i + 1];
    acc[NBF - 1] = 0.f;

    // feedback scatter (own spike, k = 250..274) — before the barrier
    {
      const u32 sp10 = pkrtz(sv, 0.f);
      CHUNK(250, sp10)
      CHUNK(255, sp10)
      CHUNK(260, sp10)
      CHUNK(265, sp10)
      CHUNK(270, sp10)
    }

    __syncthreads();   // all 600 spikes of this batch now visible in LDS

    // coupling scatter: fully unrolled over p (static selpv/sp indexing);
    // each p: gather 2 spikes from LDS, then 5 fenced 5-load chunks.
#pragma unroll
    for (int p = 0; p < 10; ++p) {
      const u32 s01 = selpv[p];
      const u32 sp2 = pkrtz(spk[pb][s01 & 0xffffu], spk[pb][s01 >> 16]);
      CHUNK(p * 25 + 0, sp2)
      CHUNK(p * 25 + 5, sp2)
      CHUNK(p * 25 + 10, sp2)
      CHUNK(p * 25 + 15, sp2)
      CHUNK(p * 25 + 20, sp2)
    }
    // no second barrier needed: next write touches spk[pb^1]; the next
    // iteration's __syncthreads orders it before any reuse of spk[pb].
  }
}

extern "C" void kernel_launch(void* const* d_in, const int* in_sizes, int n_in,
                              void* d_out, int out_size, void* d_ws, size_t ws_size,
                              hipStream_t stream) {
  const float* stim = (const float*)d_in[0];   // 32x64x64
  const float* init = (const float*)d_in[1];   // 32x600x100
  const float* spat = (const float*)d_in[2];   // 600x4096
  const float* tcf  = (const float*)d_in[3];   // 600x100
  const float* ff   = (const float*)d_in[4];   // 600x100
  const float* cf   = (const float*)d_in[5];   // 600x20x100
  const float* bias = (const float*)d_in[6];   // 600x1
  const int*   sel  = (const int*)d_in[7];     // 600x20 int32
  const float* stc  = (const float*)d_in[8];   // 500
  float* out = (float*)d_out;                  // spikes 32x600x500, gensig 32x600x400

  char* ws = (char*)d_ws;
  float* applied = (float*)ws;                       //     76,800 B
  float* convT   = (float*)(ws + 76800);             //    960,000 B
  u32*   wPT     = (u32*)(ws + 1036800);             //  2,640,000 B
  u32*   selpT   = (u32*)(ws + 3676800);             //     24,000 B
  float* initT2  = (float*)(ws + 3700800);           //  7,680,000 B (end ~11.4 MB)
  (void)ws_size; (void)in_sizes; (void)n_in; (void)out_size;

  hipLaunchKernelGGL(applied_kernel, dim3(NC, NBATCH), dim3(256), 0, stream,
                     stim, spat, applied);
  hipLaunchKernelGGL(conv_kernel, dim3((NSTEP * NC + 255) / 256), dim3(256), 0,
                     stream, stc, tcf, convT);
  hipLaunchKernelGGL(pack_kernel, dim3((NC * 1100 + 255) / 256), dim3(256), 0,
                     stream, cf, ff, wPT);
  hipLaunchKernelGGL(selp_kernel, dim3((NC * 10 + 255) / 256), dim3(256), 0,
                     stream, sel, selpT);
  hipLaunchKernelGGL(initT2_kernel, dim3((NBATCH * NBI * NC + 255) / 256),
                     dim3(256), 0, stream, init, initT2);
  hipLaunchKernelGGL(copy_init_kernel,
                     dim3((NBATCH * NC * (NBI / 4) + 255) / 256), dim3(256), 0,
                     stream, (const float4*)init, (float4*)out);
  hipLaunchKernelGGL(sim_kernel, dim3(NBATCH), dim3(NC), 0, stream,
                     bias, applied, convT, (const uint4*)wPT, selpT, initT2, out);
}

// Round 6
// 19470.694 us; speedup vs baseline: 2.2395x; 2.2395x over previous
//
#include <hip/hip_runtime.h>

// ---------------------------------------------------------------------------
// NS_Flashed_TotalSimRetina — GLM retina simulation, round 11.
// Rounds 6-10: five allocator configs all gave VGPR=84 (= arch half of the
// 168 cap for a 10-wave wg) + ~40 f32/thread scratch. Lesson: acc[100] per
// thread structurally cannot fit a 600-thread workgroup; fences don't cap
// in-flight pressure. So: SHRINK THE REGISTER STATE.
//   - taps 0..47  -> acc[48] in registers (rotate 47 movs/step)
//   - taps 48..99 -> per-cell 64-slot f32 ring in LDS (far[600][64], 153.6KB
//     of CDNA4's 160KB LDS, dynamic shared + hipFuncSetAttribute;
//     slot = (dest_step + c) & 63 -> recenter-free AND bank-conflict-free)
//   - per step: handoff ring[dest tau+48] -> acc[47]; 13 far blocks of
//     {4 LDS seed reads, 44 dot2 (11 streams), 4 LDS writes}
//   - weight table repacked: near blocks stream-major (p*12+k), far blocks
//     block-major (132 + fb*11 + p) so each far block's 11 loads are ONE
//     base + imm offsets 0..640B.
// Worst-phase pressure: 48 acc + 48 in-flight (12-block near run, even
// fully hoisted) + 11 sp + ~25 misc ~= 132 < 168 -> fits WITHOUT relying on
// scheduler fences. Expected ~3.5 us/step on 32 CUs.
// ---------------------------------------------------------------------------

#define NC     600
#define NPIX   4096
#define NBF    100
#define MC     20
#define NB     500
#define NBI    100
#define NBATCH 32
#define NSTEP  400

#define LDS_FAR_BYTES  (NC * 64 * 4)            // 153,600
#define LDS_TOTAL      (LDS_FAR_BYTES + 2 * NC * 4)  // 158,400

typedef unsigned int u32;
typedef _Float16 f16x2 __attribute__((ext_vector_type(2)));

__device__ __forceinline__ float dot2(u32 a, u32 b, float acc) {
  return __builtin_amdgcn_fdot2(__builtin_bit_cast(f16x2, a),
                                __builtin_bit_cast(f16x2, b), acc, false);
}
__device__ __forceinline__ u32 pkrtz(float a, float b) {
  return __builtin_bit_cast(u32, __builtin_amdgcn_cvt_pkrtz(a, b));
}

// --- stim_applied[b][c] = sum_p stim[b][p] * spat[c][p] ---------------------
__global__ void applied_kernel(const float* __restrict__ stim,
                               const float* __restrict__ spat,
                               float* __restrict__ applied) {
  const int c = blockIdx.x, b = blockIdx.y;
  __shared__ float red[256];
  float a = 0.f;
  for (int p = threadIdx.x; p < NPIX; p += 256)
    a += stim[b * NPIX + p] * spat[c * NPIX + p];
  red[threadIdx.x] = a;
  __syncthreads();
  for (int s = 128; s > 0; s >>= 1) {
    if (threadIdx.x < s) red[threadIdx.x] += red[threadIdx.x + s];
    __syncthreads();
  }
  if (threadIdx.x == 0) applied[b * NC + c] = red[0];
}

// --- convT[t][c] = sum_f stc[t+f] * tcf[c][f] ------------------------------
__global__ void conv_kernel(const float* __restrict__ stc,
                            const float* __restrict__ tcf,
                            float* __restrict__ convT) {
  int idx = blockIdx.x * 256 + threadIdx.x;
  if (idx >= NSTEP * NC) return;
  int t = idx / NC, c = idx - t * NC;
  float a = 0.f;
  for (int f = 0; f < NBF; ++f)
    a += stc[t + f] * tcf[c * NBF + f];
  convT[idx] = a;
}

// --- packed, time-reversed, edge-paired filter table -----------------------
// Per-cell logical stream: pair p<10 -> (cf[c][2p][99-i], cf[c][2p+1][99-i]);
// p==10 -> (ff[c][99-i], 0). Tap-block k = i>>2 (25 per stream).
// Physical block order (per 4-cell group, uint4-granular, 4-cell interleave):
//   k < 12 (near, taps 0..47):  phys = p*12 + k        (stream-major)
//   k >= 12 (far, taps 48..99): phys = 132 + (k-12)*11 + p  (block-major,
//     so the far loop's 11 stream-loads share one base + imm p*64B)
// uint4 address: ((c>>2)*275 + phys)*4 + (c&3).
__global__ void pack_kernel(const float* __restrict__ cf,
                            const float* __restrict__ ff,
                            u32* __restrict__ wPT) {
  int idx = blockIdx.x * 256 + threadIdx.x;
  if (idx >= NC * 1100) return;
  int c = idx / 1100;
  int r = idx - c * 1100;
  int p = r / 100;
  int i = r - p * 100;
  int f = 99 - i;
  float lo, hi;
  if (p < 10) {
    lo = cf[(c * MC + 2 * p) * NBF + f];
    hi = cf[(c * MC + 2 * p + 1) * NBF + f];
  } else {
    lo = ff[c * NBF + f];
    hi = 0.f;
  }
  const int k = i >> 2;
  const int phys = (k < 12) ? (p * 12 + k) : (132 + (k - 12) * 11 + p);
  wPT[((((c >> 2) * 275 + phys) * 4 + (c & 3)) << 2) + (i & 3)] = pkrtz(lo, hi);
}

// --- packed source pairs, transposed: selpT[p][c] = src0 | (src1 << 16) ----
__global__ void selp_kernel(const int* __restrict__ sel, u32* __restrict__ selpT) {
  int idx = blockIdx.x * 256 + threadIdx.x;
  if (idx >= NC * 10) return;
  int c = idx / 10, p = idx - c * 10;
  u32 s0 = (u32)sel[c * MC + 2 * p];
  u32 s1 = (u32)sel[c * MC + 2 * p + 1];
  selpT[p * NC + c] = s0 | (s1 << 16);
}

// --- initT2[b][tau][c] = init[b][c][tau]  (coalesced per-step reads) -------
__global__ void initT2_kernel(const float* __restrict__ init,
                              float* __restrict__ initT2) {
  int idx = blockIdx.x * 256 + threadIdx.x;
  if (idx >= NBATCH * NBI * NC) return;
  int c = idx % NC;
  int r = idx / NC;
  int tau = r % NBI;
  int b = r / NBI;
  initT2[idx] = init[(b * NC + c) * NBI + tau];
}

// --- copy initial spikes into output (first 100 bins of each row) ----------
__global__ void copy_init_kernel(const float4* __restrict__ init,
                                 float4* __restrict__ out) {
  int idx = blockIdx.x * 256 + threadIdx.x;
  if (idx >= NBATCH * NC * (NBI / 4)) return;
  int k4 = idx % (NBI / 4);
  int bc = idx / (NBI / 4);
  out[bc * (NB / 4) + k4] = init[idx];
}

// one far-stream update: block load at imm offset (PP)*64B, 4 dot2
#define FARDOT(PP, SPV)                                                      \
  {                                                                          \
    const uint4 w = wf[(PP) * 4];                                            \
    d0 = dot2(w.x, SPV, d0);                                                 \
    d1 = dot2(w.y, SPV, d1);                                                 \
    d2 = dot2(w.z, SPV, d2);                                                 \
    d3 = dot2(w.w, SPV, d3);                                                 \
  }

// one near tap-block: load at imm offset (KB)*64B, 4 dot2 into acc
#define NEARBLK(WB, KB, SPV)                                                 \
  {                                                                          \
    const uint4 w = (WB)[(KB) * 4];                                          \
    acc[(KB) * 4 + 0] = dot2(w.x, SPV, acc[(KB) * 4 + 0]);                   \
    acc[(KB) * 4 + 1] = dot2(w.y, SPV, acc[(KB) * 4 + 1]);                   \
    acc[(KB) * 4 + 2] = dot2(w.z, SPV, acc[(KB) * 4 + 2]);                   \
    acc[(KB) * 4 + 3] = dot2(w.w, SPV, acc[(KB) * 4 + 3]);                   \
  }

// --- the recurrence: one wg per batch; acc[48] regs + 64-slot LDS far ring -
__global__ __attribute__((amdgpu_flat_work_group_size(NC, NC)))
void sim_kernel(
    const float* __restrict__ bias, const float* __restrict__ applied,
    const float* __restrict__ convT, const uint4* __restrict__ wp,
    const u32* __restrict__ selpT, const float* __restrict__ initT2,
    float* __restrict__ out) {
  extern __shared__ char smem[];
  float* __restrict__ farb = (float*)smem;                    // [600][64]
  float* __restrict__ spkb = (float*)(smem + LDS_FAR_BYTES);  // [2][600]

  const int c = threadIdx.x;     // cell, 0..599
  const int b = blockIdx.x;      // batch, 0..31
  float* __restrict__ fr = farb + c * 64;

  // zero the far ring (256B-aligned per thread)
#pragma unroll
  for (int s4 = 0; s4 < 16; ++s4)
    ((float4*)fr)[s4] = float4{0.f, 0.f, 0.f, 0.f};

  float acc[48];
#pragma unroll
  for (int i = 0; i < 48; ++i) acc[i] = 0.f;

  const float biasv = bias[c];
  const float appv  = applied[b * NC + c];
  const float* ib2  = initT2 + (size_t)b * NBI * NC;
  float* outS = out + (size_t)(b * NC + c) * NB + NBI;
  float* outG = out + (size_t)NBATCH * NC * NB + (size_t)(b * NC + c) * NSTEP;

  // single per-lane weight base (4-cell interleave): block k at wc[k*4]
  const uint4* __restrict__ wc  = wp + ((c >> 2) * 1100 + (c & 3));
  const uint4* __restrict__ vfb = wc + 480;  // feedback near blocks (120..131)

  __syncthreads();  // far ring zeroed before anyone scatters

#pragma unroll 1
  for (int tau = 0; tau < NB; ++tau) {
    const int t   = tau - NBI;
    const int pb6 = (tau & 1) * NC;
    float sv;
    if (t >= 0) {
      float g = biasv + appv * convT[t * NC + c] + acc[0];
      sv = 1.f / (1.f + __expf(-g));
      outS[t] = sv;
      outG[t] = g;
    } else {
      sv = ib2[tau * NC + c];
    }
    spkb[pb6 + c] = sv;

    // rotate: acc[i] <- contributions to step (tau+1)+i
#pragma unroll
    for (int i = 0; i < 47; ++i) acc[i] = acc[i + 1];

    // handoff: dest tau+48 leaves the ring, enters the register window;
    // slot is retired to 0 (it will re-accumulate dest tau+112 from step
    // tau+12 onward). This step's far writes touch dests tau+49..tau+100,
    // which never alias slot (tau+48+c)&63.
    {
      const int hs = (tau + 48 + c) & 63;
      acc[47] = fr[hs];
      fr[hs] = 0.f;
    }

    // feedback near scatter (own spike, taps 0..47) — before the barrier
    const u32 sp10 = pkrtz(sv, 0.f);
    NEARBLK(vfb, 0, sp10)  NEARBLK(vfb, 1, sp10)  NEARBLK(vfb, 2, sp10)
    NEARBLK(vfb, 3, sp10)  NEARBLK(vfb, 4, sp10)  NEARBLK(vfb, 5, sp10)
    NEARBLK(vfb, 6, sp10)  NEARBLK(vfb, 7, sp10)  NEARBLK(vfb, 8, sp10)
    NEARBLK(vfb, 9, sp10)  NEARBLK(vfb, 10, sp10) NEARBLK(vfb, 11, sp10)

    __syncthreads();   // all 600 spikes of this batch now visible in LDS

    // gather the 10 coupled spike-pairs (named scalars -> no scratch array)
    const u32 q0 = selpT[0 * NC + c], q1 = selpT[1 * NC + c];
    const u32 q2 = selpT[2 * NC + c], q3 = selpT[3 * NC + c];
    const u32 q4 = selpT[4 * NC + c], q5 = selpT[5 * NC + c];
    const u32 q6 = selpT[6 * NC + c], q7 = selpT[7 * NC + c];
    const u32 q8 = selpT[8 * NC + c], q9 = selpT[9 * NC + c];
    const u32 f0 = pkrtz(spkb[pb6 + (q0 & 0xffffu)], spkb[pb6 + (q0 >> 16)]);
    const u32 f1 = pkrtz(spkb[pb6 + (q1 & 0xffffu)], spkb[pb6 + (q1 >> 16)]);
    const u32 f2 = pkrtz(spkb[pb6 + (q2 & 0xffffu)], spkb[pb6 + (q2 >> 16)]);
    const u32 f3 = pkrtz(spkb[pb6 + (q3 & 0xffffu)], spkb[pb6 + (q3 >> 16)]);
    const u32 f4 = pkrtz(spkb[pb6 + (q4 & 0xffffu)], spkb[pb6 + (q4 >> 16)]);
    const u32 f5 = pkrtz(spkb[pb6 + (q5 & 0xffffu)], spkb[pb6 + (q5 >> 16)]);
    const u32 f6 = pkrtz(spkb[pb6 + (q6 & 0xffffu)], spkb[pb6 + (q6 >> 16)]);
    const u32 f7 = pkrtz(spkb[pb6 + (q7 & 0xffffu)], spkb[pb6 + (q7 >> 16)]);
    const u32 f8 = pkrtz(spkb[pb6 + (q8 & 0xffffu)], spkb[pb6 + (q8 >> 16)]);
    const u32 f9 = pkrtz(spkb[pb6 + (q9 & 0xffffu)], spkb[pb6 + (q9 >> 16)]);

    // far scatter: taps 48+4fb+j (all 11 streams) -> ring slots, RMW.
    // Seeds double as accumulators: 4 reads, 44 dot2, 4 writes per block.
#pragma unroll 1
    for (int fb = 0; fb < 13; ++fb) {
      const int sb = tau + 49 + 4 * fb + c;
      const int a0 = (sb + 0) & 63, a1 = (sb + 1) & 63;
      const int a2 = (sb + 2) & 63, a3 = (sb + 3) & 63;
      float d0 = fr[a0], d1 = fr[a1], d2 = fr[a2], d3 = fr[a3];
      const uint4* __restrict__ wf = wc + (132 + fb * 11) * 4;
      FARDOT(0, f0) FARDOT(1, f1) FARDOT(2, f2) FARDOT(3, f3) FARDOT(4, f4)
      FARDOT(5, f5) FARDOT(6, f6) FARDOT(7, f7) FARDOT(8, f8) FARDOT(9, f9)
      FARDOT(10, sp10)
      fr[a0] = d0; fr[a1] = d1; fr[a2] = d2; fr[a3] = d3;
    }

    // near coupling scatter: taps 0..47 of each pair-stream into acc
#pragma unroll 1
    for (int p = 0; p < 10; ++p) {
      const u32 s01 = selpT[p * NC + c];                   // L1-hot reload
      const u32 sp2 = pkrtz(spkb[pb6 + (s01 & 0xffffu)],
                            spkb[pb6 + (s01 >> 16)]);
      const uint4* __restrict__ wn = wc + p * 48;          // block p*12
      NEARBLK(wn, 0, sp2)  NEARBLK(wn, 1, sp2)  NEARBLK(wn, 2, sp2)
      NEARBLK(wn, 3, sp2)  NEARBLK(wn, 4, sp2)  NEARBLK(wn, 5, sp2)
      NEARBLK(wn, 6, sp2)  NEARBLK(wn, 7, sp2)  NEARBLK(wn, 8, sp2)
      NEARBLK(wn, 9, sp2)  NEARBLK(wn, 10, sp2) NEARBLK(wn, 11, sp2)
    }
    // next iteration's spk write targets the other parity buffer; its
    // __syncthreads orders everything before reuse.
  }
}

extern "C" void kernel_launch(void* const* d_in, const int* in_sizes, int n_in,
                              void* d_out, int out_size, void* d_ws, size_t ws_size,
                              hipStream_t stream) {
  const float* stim = (const float*)d_in[0];   // 32x64x64
  const float* init = (const float*)d_in[1];   // 32x600x100
  const float* spat = (const float*)d_in[2];   // 600x4096
  const float* tcf  = (const float*)d_in[3];   // 600x100
  const float* ff   = (const float*)d_in[4];   // 600x100
  const float* cf   = (const float*)d_in[5];   // 600x20x100
  const float* bias = (const float*)d_in[6];   // 600x1
  const int*   sel  = (const int*)d_in[7];     // 600x20 int32
  const float* stc  = (const float*)d_in[8];   // 500
  float* out = (float*)d_out;                  // spikes 32x600x500, gensig 32x600x400

  char* ws = (char*)d_ws;
  float* applied = (float*)ws;                       //     76,800 B
  float* convT   = (float*)(ws + 76800);             //    960,000 B
  u32*   wPT     = (u32*)(ws + 1036800);             //  2,640,000 B
  u32*   selpT   = (u32*)(ws + 3676800);             //     24,000 B
  float* initT2  = (float*)(ws + 3700800);           //  7,680,000 B (end ~11.4 MB)
  (void)ws_size; (void)in_sizes; (void)n_in; (void)out_size;

  // opt in to >64KB dynamic LDS (CDNA4: 160KB/CU); idempotent, host-side,
  // graph-capture-safe (not a stream op, not an alloc/sync).
  static int lds_opted = 0;
  if (!lds_opted) {
    hipFuncSetAttribute((const void*)sim_kernel,
                        hipFuncAttributeMaxDynamicSharedMemorySize, LDS_TOTAL);
    lds_opted = 1;
  }

  hipLaunchKernelGGL(applied_kernel, dim3(NC, NBATCH), dim3(256), 0, stream,
                     stim, spat, applied);
  hipLaunchKernelGGL(conv_kernel, dim3((NSTEP * NC + 255) / 256), dim3(256), 0,
                     stream, stc, tcf, convT);
  hipLaunchKernelGGL(pack_kernel, dim3((NC * 1100 + 255) / 256), dim3(256), 0,
                     stream, cf, ff, wPT);
  hipLaunchKernelGGL(selp_kernel, dim3((NC * 10 + 255) / 256), dim3(256), 0,
                     stream, sel, selpT);
  hipLaunchKernelGGL(initT2_kernel, dim3((NBATCH * NBI * NC + 255) / 256),
                     dim3(256), 0, stream, init, initT2);
  hipLaunchKernelGGL(copy_init_kernel,
                     dim3((NBATCH * NC * (NBI / 4) + 255) / 256), dim3(256), 0,
                     stream, (const float4*)init, (float4*)out);
  hipLaunchKernelGGL(sim_kernel, dim3(NBATCH), dim3(NC), LDS_TOTAL, stream,
                     bias, applied, convT, (const uint4*)wPT, selpT, initT2, out);
}

// Round 7
// 12495.517 us; speedup vs baseline: 3.4896x; 1.5582x over previous
//
#include <hip/hip_runtime.h>

// ---------------------------------------------------------------------------
// NS_Flashed_TotalSimRetina — GLM retina simulation, round 12.
// Round 11 (acc[48] regs + LDS far ring) removed the spill (VGPR 80, FETCH
// 53MB) but landed at 49us/step with all pipes ~idle: an L1 STREAMING WALL —
// each CU pulls the whole 2.64MB weight table through its 32KB L1 every
// step (41,250 64B lines/step, all misses; ~0.35-1 line/cyc => 17-49us).
// Fix: R=4 GROUP BATCHING. Per weight uint4 loaded, do 16 dot2 (4 taps x 4
// sources) instead of 4 -> weight lines/step /4. The serial sigmoid chain
// is preserved by splitting in-group contributions (tap i, source m with
// i+m<=2 -> dest inside the group) into a tiny correction at generation
// time (66 dot2/group from a 79KB head table); all (i+m>=3) contributions
// batch into the acc window / far ring exactly as before. dot2 count
// conserved (4400/group == 1100/step). Spikes now in a 4-deep fp16 LDS
// buffer (spkh[4][600], 4.8KB; ring 153.6KB -> total 158.4KB as before).
// Streams unified: selpT gets an 11th row (c,c) so feedback goes through
// the same coupling path (its packed weights already have hi=0).
// ---------------------------------------------------------------------------

#define NC     600
#define NPIX   4096
#define NBF    100
#define MC     20
#define NB     500
#define NBI    100
#define NBATCH 32
#define NSTEP  400

#define LDS_FAR_BYTES (NC * 64 * 4)                     // 153,600
#define LDS_TOTAL     (LDS_FAR_BYTES + 4 * NC * 2)      // 158,400

typedef unsigned int u32;
typedef _Float16 f16x2 __attribute__((ext_vector_type(2)));

__device__ __forceinline__ float dot2(u32 a, u32 b, float acc) {
  return __builtin_amdgcn_fdot2(__builtin_bit_cast(f16x2, a),
                                __builtin_bit_cast(f16x2, b), acc, false);
}
__device__ __forceinline__ u32 pkrtz(float a, float b) {
  return __builtin_bit_cast(u32, __builtin_amdgcn_cvt_pkrtz(a, b));
}

// --- stim_applied[b][c] = sum_p stim[b][p] * spat[c][p] ---------------------
__global__ void applied_kernel(const float* __restrict__ stim,
                               const float* __restrict__ spat,
                               float* __restrict__ applied) {
  const int c = blockIdx.x, b = blockIdx.y;
  __shared__ float red[256];
  float a = 0.f;
  for (int p = threadIdx.x; p < NPIX; p += 256)
    a += stim[b * NPIX + p] * spat[c * NPIX + p];
  red[threadIdx.x] = a;
  __syncthreads();
  for (int s = 128; s > 0; s >>= 1) {
    if (threadIdx.x < s) red[threadIdx.x] += red[threadIdx.x + s];
    __syncthreads();
  }
  if (threadIdx.x == 0) applied[b * NC + c] = red[0];
}

// --- convT[t][c] = sum_f stc[t+f] * tcf[c][f] ------------------------------
__global__ void conv_kernel(const float* __restrict__ stc,
                            const float* __restrict__ tcf,
                            float* __restrict__ convT) {
  int idx = blockIdx.x * 256 + threadIdx.x;
  if (idx >= NSTEP * NC) return;
  int t = idx / NC, c = idx - t * NC;
  float a = 0.f;
  for (int f = 0; f < NBF; ++f)
    a += stc[t + f] * tcf[c * NBF + f];
  convT[idx] = a;
}

// --- packed, time-reversed, edge-paired filter table (round-11 layout) -----
// Per-cell stream: pair p<10 -> (cf[c][2p][99-i], cf[c][2p+1][99-i]);
// p==10 -> (ff[c][99-i], 0). Tap-block k = i>>2.
//   k < 12 (taps 0..47):  phys = p*12 + k            (stream-major)
//   k >= 12 (taps 48..99): phys = 132 + (k-12)*11 + p (block-major)
// uint4 address: ((c>>2)*275 + phys)*4 + (c&3)  (4-cell interleave).
__global__ void pack_kernel(const float* __restrict__ cf,
                            const float* __restrict__ ff,
                            u32* __restrict__ wPT) {
  int idx = blockIdx.x * 256 + threadIdx.x;
  if (idx >= NC * 1100) return;
  int c = idx / 1100;
  int r = idx - c * 1100;
  int p = r / 100;
  int i = r - p * 100;
  int f = 99 - i;
  float lo, hi;
  if (p < 10) {
    lo = cf[(c * MC + 2 * p) * NBF + f];
    hi = cf[(c * MC + 2 * p + 1) * NBF + f];
  } else {
    lo = ff[c * NBF + f];
    hi = 0.f;
  }
  const int k = i >> 2;
  const int phys = (k < 12) ? (p * 12 + k) : (132 + (k - 12) * 11 + p);
  wPT[((((c >> 2) * 275 + k * 0 + phys) * 4 + (c & 3)) << 2) + (i & 3)] =
      pkrtz(lo, hi);
}

// --- head table: head[d][s][c] = packed tap-d weights (d=0..2) -------------
__global__ void head_kernel(const float* __restrict__ cf,
                            const float* __restrict__ ff,
                            u32* __restrict__ head) {
  int idx = blockIdx.x * 256 + threadIdx.x;
  if (idx >= 3 * 11 * NC) return;
  int c = idx % NC;
  int r = idx / NC;
  int s = r % 11;
  int d = r / 11;
  int f = 99 - d;
  float lo, hi;
  if (s < 10) {
    lo = cf[(c * MC + 2 * s) * NBF + f];
    hi = cf[(c * MC + 2 * s + 1) * NBF + f];
  } else {
    lo = ff[c * NBF + f];
    hi = 0.f;
  }
  head[(d * 11 + s) * NC + c] = pkrtz(lo, hi);
}

// --- packed source pairs, 11 rows: row 10 = (c, c) for feedback ------------
__global__ void selp_kernel(const int* __restrict__ sel, u32* __restrict__ selpT) {
  int idx = blockIdx.x * 256 + threadIdx.x;
  if (idx >= NC * 11) return;
  int c = idx % NC, p = idx / NC;
  u32 v;
  if (p < 10) {
    u32 s0 = (u32)sel[c * MC + 2 * p];
    u32 s1 = (u32)sel[c * MC + 2 * p + 1];
    v = s0 | (s1 << 16);
  } else {
    v = (u32)c | ((u32)c << 16);
  }
  selpT[p * NC + c] = v;
}

// --- initT2[b][tau][c] = init[b][c][tau]  (coalesced per-step reads) -------
__global__ void initT2_kernel(const float* __restrict__ init,
                              float* __restrict__ initT2) {
  int idx = blockIdx.x * 256 + threadIdx.x;
  if (idx >= NBATCH * NBI * NC) return;
  int c = idx % NC;
  int r = idx / NC;
  int tau = r % NBI;
  int b = r / NBI;
  initT2[idx] = init[(b * NC + c) * NBI + tau];
}

// --- copy initial spikes into output (first 100 bins of each row) ----------
__global__ void copy_init_kernel(const float4* __restrict__ init,
                                 float4* __restrict__ out) {
  int idx = blockIdx.x * 256 + threadIdx.x;
  if (idx >= NBATCH * NC * (NBI / 4)) return;
  int k4 = idx % (NBI / 4);
  int bc = idx / (NBI / 4);
  out[bc * (NB / 4) + k4] = init[idx];
}

// 16 dot2 of one near block KB (1..11): dest acc[4KB-3 .. 4KB+3]
#define NB16(WB, KB)                                                          \
  {                                                                           \
    const uint4 w = (WB)[(KB) * 4];                                           \
    acc[4*(KB)-3] = dot2(w.x, F0, acc[4*(KB)-3]);                             \
    acc[4*(KB)-2] = dot2(w.x, F1, acc[4*(KB)-2]);                             \
    acc[4*(KB)-1] = dot2(w.x, F2, acc[4*(KB)-1]);                             \
    acc[4*(KB)+0] = dot2(w.x, F3, acc[4*(KB)+0]);                             \
    acc[4*(KB)-2] = dot2(w.y, F0, acc[4*(KB)-2]);                             \
    acc[4*(KB)-1] = dot2(w.y, F1, acc[4*(KB)-1]);                             \
    acc[4*(KB)+0] = dot2(w.y, F2, acc[4*(KB)+0]);                             \
    acc[4*(KB)+1] = dot2(w.y, F3, acc[4*(KB)+1]);                             \
    acc[4*(KB)-1] = dot2(w.z, F0, acc[4*(KB)-1]);                             \
    acc[4*(KB)+0] = dot2(w.z, F1, acc[4*(KB)+0]);                             \
    acc[4*(KB)+1] = dot2(w.z, F2, acc[4*(KB)+1]);                             \
    acc[4*(KB)+2] = dot2(w.z, F3, acc[4*(KB)+2]);                             \
    acc[4*(KB)+0] = dot2(w.w, F0, acc[4*(KB)+0]);                             \
    acc[4*(KB)+1] = dot2(w.w, F1, acc[4*(KB)+1]);                             \
    acc[4*(KB)+2] = dot2(w.w, F2, acc[4*(KB)+2]);                             \
    acc[4*(KB)+3] = dot2(w.w, F3, acc[4*(KB)+3]);                             \
  }

// 16 dot2 of one far block for stream P (literal): dests d0..d6
#define FD16(P)                                                               \
  {                                                                           \
    const uint4 w = wf[(P) * 4];                                              \
    d0 = dot2(w.x, fv[P][0], d0); d1 = dot2(w.x, fv[P][1], d1);               \
    d2 = dot2(w.x, fv[P][2], d2); d3 = dot2(w.x, fv[P][3], d3);               \
    d1 = dot2(w.y, fv[P][0], d1); d2 = dot2(w.y, fv[P][1], d2);               \
    d3 = dot2(w.y, fv[P][2], d3); d4 = dot2(w.y, fv[P][3], d4);               \
    d2 = dot2(w.z, fv[P][0], d2); d3 = dot2(w.z, fv[P][1], d3);               \
    d4 = dot2(w.z, fv[P][2], d4); d5 = dot2(w.z, fv[P][3], d5);               \
    d3 = dot2(w.w, fv[P][0], d3); d4 = dot2(w.w, fv[P][1], d4);               \
    d5 = dot2(w.w, fv[P][2], d5); d6 = dot2(w.w, fv[P][3], d6);               \
  }

// in-group correction: dest gen J, source M, tap D=J-M-1 (all literals)
#define CORR(D, M)                                                            \
  _Pragma("unroll")                                                           \
  for (int p = 0; p < 11; ++p)                                                \
    g = dot2(hd[((D) * 11 + p) * NC + c], fv[p][M], g);

#define GATHER(J)                                                             \
  _Pragma("unroll")                                                           \
  for (int p = 0; p < 11; ++p) {                                              \
    const u32 s01 = selpT[p * NC + c];                                        \
    fv[p][J] = (u32)spkh[(J) * NC + (s01 & 0xffffu)]                          \
             | ((u32)spkh[(J) * NC + (s01 >> 16)] << 16);                     \
  }

#define SUB_GEN(J, ...)                                                       \
  {                                                                           \
    const int t = G + (J) - NBI;                                              \
    float g = biasv + appv * convT[t * NC + c] + acc[J];                      \
    __VA_ARGS__                                                               \
    const float sv = 1.f / (1.f + __expf(-g));                                \
    outS[t] = sv;                                                             \
    outG[t] = g;                                                              \
    const u32 pk = pkrtz(sv, 0.f);                                            \
    spkh[(J) * NC + c] = (unsigned short)pk;                                  \
    __syncthreads();                                                          \
    GATHER(J)                                                                 \
  }

#define SUB_INI(J)                                                            \
  {                                                                           \
    const float sv = ib2[(G + (J)) * NC + c];                                 \
    const u32 pk = pkrtz(sv, 0.f);                                            \
    spkh[(J) * NC + c] = (unsigned short)pk;                                  \
    __syncthreads();                                                          \
    GATHER(J)                                                                 \
  }

// --- the recurrence: one wg per batch; R=4 group-batched scatter -----------
__global__ __attribute__((amdgpu_flat_work_group_size(NC, NC)))
void sim_kernel(
    const float* __restrict__ bias, const float* __restrict__ applied,
    const float* __restrict__ convT, const uint4* __restrict__ wp,
    const u32* __restrict__ selpT, const u32* __restrict__ hd,
    const float* __restrict__ initT2, float* __restrict__ out) {
  extern __shared__ char smem[];
  float* __restrict__ farb = (float*)smem;                             // [600][64]
  unsigned short* __restrict__ spkh =
      (unsigned short*)(smem + LDS_FAR_BYTES);                         // [4][600]

  const int c = threadIdx.x;     // cell, 0..599
  const int b = blockIdx.x;      // batch, 0..31
  float* __restrict__ fr = farb + c * 64;

#pragma unroll
  for (int s4 = 0; s4 < 16; ++s4)
    ((float4*)fr)[s4] = float4{0.f, 0.f, 0.f, 0.f};

  float acc[48];
#pragma unroll
  for (int i = 0; i < 48; ++i) acc[i] = 0.f;

  u32 fv[11][4];                 // packed spike pairs, all static-indexed

  const float biasv = bias[c];
  const float appv  = applied[b * NC + c];
  const float* ib2  = initT2 + (size_t)b * NBI * NC;
  float* outS = out + (size_t)(b * NC + c) * NB + NBI;
  float* outG = out + (size_t)NBATCH * NC * NB + (size_t)(b * NC + c) * NSTEP;

  // single per-lane weight base (4-cell interleave): block phys at wc[phys*4]
  const uint4* __restrict__ wc = wp + ((c >> 2) * 1100 + (c & 3));

  __syncthreads();  // far ring zeroed before anyone scatters

#pragma unroll 1
  for (int G = 0; G < NB; G += 4) {
    // ---- 4 generation sub-steps (1 barrier each, same as before) ----
    if (G >= NBI) {
      SUB_GEN(0, )
      SUB_GEN(1, CORR(0, 0))
      SUB_GEN(2, CORR(1, 0) CORR(0, 1))
      SUB_GEN(3, CORR(2, 0) CORR(1, 1) CORR(0, 2))
    } else {
      SUB_INI(0) SUB_INI(1) SUB_INI(2) SUB_INI(3)
    }
    if (G + 4 >= NB) break;

    // ---- rotate window by 4 + ring handoff (dests G+48..G+51) ----
#pragma unroll
    for (int i = 0; i < 44; ++i) acc[i] = acc[i + 4];
#pragma unroll
    for (int r = 0; r < 4; ++r) {
      const int hs = (G + 48 + r + c) & 63;
      acc[44 + r] = fr[hs];
      fr[hs] = 0.f;
    }

    // ---- straddle seeds: ring dests G'+48..G'+51 (G' = G+4) ----
    const int sb0 = G + 52 + c;
    float e0 = fr[sb0 & 63], e1 = fr[(sb0 + 1) & 63];
    float e2 = fr[(sb0 + 2) & 63], e3 = fr[(sb0 + 3) & 63];

    // ---- near + straddle scatter: rolled over the 11 streams ----
#pragma unroll 1
    for (int p = 0; p < 11; ++p) {
      const u32 s01 = selpT[p * NC + c];
      const int lo = (int)(s01 & 0xffffu), hi = (int)(s01 >> 16);
      const u32 F0 = (u32)spkh[0 * NC + lo] | ((u32)spkh[0 * NC + hi] << 16);
      const u32 F1 = (u32)spkh[1 * NC + lo] | ((u32)spkh[1 * NC + hi] << 16);
      const u32 F2 = (u32)spkh[2 * NC + lo] | ((u32)spkh[2 * NC + hi] << 16);
      const u32 F3 = (u32)spkh[3 * NC + lo] | ((u32)spkh[3 * NC + hi] << 16);
      const uint4* __restrict__ wn = wc + p * 48;
      {  // block 0: triangular (i+m>=3 only; i+m<=2 went via CORR)
        const uint4 w = wn[0];
        acc[0] = dot2(w.x, F3, acc[0]);
        acc[0] = dot2(w.y, F2, acc[0]); acc[1] = dot2(w.y, F3, acc[1]);
        acc[0] = dot2(w.z, F1, acc[0]); acc[1] = dot2(w.z, F2, acc[1]);
        acc[2] = dot2(w.z, F3, acc[2]);
        acc[0] = dot2(w.w, F0, acc[0]); acc[1] = dot2(w.w, F1, acc[1]);
        acc[2] = dot2(w.w, F2, acc[2]); acc[3] = dot2(w.w, F3, acc[3]);
      }
      NB16(wn, 1) NB16(wn, 2) NB16(wn, 3) NB16(wn, 4)
      __builtin_amdgcn_sched_barrier(0);
      NB16(wn, 5) NB16(wn, 6) NB16(wn, 7) NB16(wn, 8)
      __builtin_amdgcn_sched_barrier(0);
      NB16(wn, 9) NB16(wn, 10) NB16(wn, 11)
      {  // straddle block (taps 48..51): acc 45..47 + ring e0..e3
        const uint4 w = wc[(132 + p) * 4];
        acc[45] = dot2(w.x, F0, acc[45]); acc[46] = dot2(w.x, F1, acc[46]);
        acc[47] = dot2(w.x, F2, acc[47]); e0 = dot2(w.x, F3, e0);
        acc[46] = dot2(w.y, F0, acc[46]); acc[47] = dot2(w.y, F1, acc[47]);
        e0 = dot2(w.y, F2, e0); e1 = dot2(w.y, F3, e1);
        acc[47] = dot2(w.z, F0, acc[47]); e0 = dot2(w.z, F1, e0);
        e1 = dot2(w.z, F2, e1); e2 = dot2(w.z, F3, e2);
        e0 = dot2(w.w, F0, e0); e1 = dot2(w.w, F1, e1);
        e2 = dot2(w.w, F2, e2); e3 = dot2(w.w, F3, e3);
      }
      __builtin_amdgcn_sched_barrier(0);
    }
    fr[sb0 & 63] = e0; fr[(sb0 + 1) & 63] = e1;
    fr[(sb0 + 2) & 63] = e2; fr[(sb0 + 3) & 63] = e3;

    // ---- far scatter: 12 blocks, 7-slot ring RMW each ----
#pragma unroll 1
    for (int fb = 1; fb <= 12; ++fb) {
      const int sb = G + 49 + 4 * fb + c;   // dest G'+ (4(fb+12)-3)
      const int a0 = sb & 63, a1 = (sb + 1) & 63, a2 = (sb + 2) & 63,
                a3 = (sb + 3) & 63, a4 = (sb + 4) & 63, a5 = (sb + 5) & 63,
                a6 = (sb + 6) & 63;
      float d0 = fr[a0], d1 = fr[a1], d2 = fr[a2], d3 = fr[a3];
      float d4 = fr[a4], d5 = fr[a5], d6 = fr[a6];
      const uint4* __restrict__ wf = wc + (132 + fb * 11) * 4;
      FD16(0) FD16(1) FD16(2) FD16(3)
      __builtin_amdgcn_sched_barrier(0);
      FD16(4) FD16(5) FD16(6) FD16(7)
      __builtin_amdgcn_sched_barrier(0);
      FD16(8) FD16(9) FD16(10)
      fr[a0] = d0; fr[a1] = d1; fr[a2] = d2; fr[a3] = d3;
      fr[a4] = d4; fr[a5] = d5; fr[a6] = d6;
    }
  }
}

extern "C" void kernel_launch(void* const* d_in, const int* in_sizes, int n_in,
                              void* d_out, int out_size, void* d_ws, size_t ws_size,
                              hipStream_t stream) {
  const float* stim = (const float*)d_in[0];   // 32x64x64
  const float* init = (const float*)d_in[1];   // 32x600x100
  const float* spat = (const float*)d_in[2];   // 600x4096
  const float* tcf  = (const float*)d_in[3];   // 600x100
  const float* ff   = (const float*)d_in[4];   // 600x100
  const float* cf   = (const float*)d_in[5];   // 600x20x100
  const float* bias = (const float*)d_in[6];   // 600x1
  const int*   sel  = (const int*)d_in[7];     // 600x20 int32
  const float* stc  = (const float*)d_in[8];   // 500
  float* out = (float*)d_out;                  // spikes 32x600x500, gensig 32x600x400

  char* ws = (char*)d_ws;
  float* applied = (float*)ws;                       //     76,800 B
  float* convT   = (float*)(ws + 76800);             //    960,000 B
  u32*   wPT     = (u32*)(ws + 1036800);             //  2,640,000 B
  u32*   selpT   = (u32*)(ws + 3676800);             //     26,400 B
  u32*   head    = (u32*)(ws + 3703200);             //     79,200 B
  float* initT2  = (float*)(ws + 3782400);           //  7,680,000 B (end ~11.5 MB)
  (void)ws_size; (void)in_sizes; (void)n_in; (void)out_size;

  static int lds_opted = 0;
  if (!lds_opted) {
    hipFuncSetAttribute((const void*)sim_kernel,
                        hipFuncAttributeMaxDynamicSharedMemorySize, LDS_TOTAL);
    lds_opted = 1;
  }

  hipLaunchKernelGGL(applied_kernel, dim3(NC, NBATCH), dim3(256), 0, stream,
                     stim, spat, applied);
  hipLaunchKernelGGL(conv_kernel, dim3((NSTEP * NC + 255) / 256), dim3(256), 0,
                     stream, stc, tcf, convT);
  hipLaunchKernelGGL(pack_kernel, dim3((NC * 1100 + 255) / 256), dim3(256), 0,
                     stream, cf, ff, wPT);
  hipLaunchKernelGGL(head_kernel, dim3((3 * 11 * NC + 255) / 256), dim3(256), 0,
                     stream, cf, ff, head);
  hipLaunchKernelGGL(selp_kernel, dim3((NC * 11 + 255) / 256), dim3(256), 0,
                     stream, sel, selpT);
  hipLaunchKernelGGL(initT2_kernel, dim3((NBATCH * NBI * NC + 255) / 256),
                     dim3(256), 0, stream, init, initT2);
  hipLaunchKernelGGL(copy_init_kernel,
                     dim3((NBATCH * NC * (NBI / 4) + 255) / 256), dim3(256), 0,
                     stream, (const float4*)init, (float4*)out);
  hipLaunchKernelGGL(sim_kernel, dim3(NBATCH), dim3(NC), LDS_TOTAL, stream,
                     bias, applied, convT, (const uint4*)wPT, selpT, head,
                     initT2, out);
}

// Round 8
// 9966.135 us; speedup vs baseline: 4.3753x; 1.2538x over previous
//
#include <hip/hip_runtime.h>

// ---------------------------------------------------------------------------
// NS_Flashed_TotalSimRetina — GLM retina simulation, round 13.
// Round 12 (R=4 batching) = 12.3ms. Counters: weight L1-stream wall 118K
// cyc/group (41,250 64B lines through 32KB L1 at ~0.35 lines/cyc) + ~40K cyc
// of AGPR-copy tax (persistent fv[11][4] + acc[48] > 84 arch VGPRs).
// This round:
//   - R=8 group batching: weight lines per STEP halve again (each uint4
//     drives 32 dot2). dot2 conserved: 8800/group = 8x1100.
//   - ZERO persistent fv: in-group corrections become a HEAD-SCATTER (after
//     sub-step M's barrier, scatter source M's tap-(0..6) terms straight
//     into acc[M+1..7], 308 dot2 total, off the sigmoid dep chain); near
//     loop re-gathers per stream; far scatter in 3 passes with transient
//     fa[4][8]=32 regs. Persistent state = acc[48] + ~15 scalars.
//   - trailing group barrier fixes a latent spkh WAR race (r12 heritage).
// Layout: near blocks k=0..13 stream-major (p*14+k), far k=14..24
// block-major (154+(k-14)*11+p). spkh[8][600] fp16; ring [600][64] f32.
// LDS 163,200B. Straddle (blocks 12,13) -> acc tail + 8 ring temps.
// ---------------------------------------------------------------------------

#define NC     600
#define NPIX   4096
#define NBF    100
#define MC     20
#define NB     500
#define NBI    100
#define NBATCH 32
#define NSTEP  400

#define LDS_FAR_BYTES (NC * 64 * 4)                 // 153,600
#define LDS_TOTAL     (LDS_FAR_BYTES + 8 * NC * 2)  // 163,200

typedef unsigned int u32;
typedef _Float16 f16x2 __attribute__((ext_vector_type(2)));

__device__ __forceinline__ float dot2(u32 a, u32 b, float acc) {
  return __builtin_amdgcn_fdot2(__builtin_bit_cast(f16x2, a),
                                __builtin_bit_cast(f16x2, b), acc, false);
}
__device__ __forceinline__ u32 pkrtz(float a, float b) {
  return __builtin_bit_cast(u32, __builtin_amdgcn_cvt_pkrtz(a, b));
}

// --- stim_applied[b][c] = sum_p stim[b][p] * spat[c][p] ---------------------
__global__ void applied_kernel(const float* __restrict__ stim,
                               const float* __restrict__ spat,
                               float* __restrict__ applied) {
  const int c = blockIdx.x, b = blockIdx.y;
  __shared__ float red[256];
  float a = 0.f;
  for (int p = threadIdx.x; p < NPIX; p += 256)
    a += stim[b * NPIX + p] * spat[c * NPIX + p];
  red[threadIdx.x] = a;
  __syncthreads();
  for (int s = 128; s > 0; s >>= 1) {
    if (threadIdx.x < s) red[threadIdx.x] += red[threadIdx.x + s];
    __syncthreads();
  }
  if (threadIdx.x == 0) applied[b * NC + c] = red[0];
}

// --- convT[t][c] = sum_f stc[t+f] * tcf[c][f] ------------------------------
__global__ void conv_kernel(const float* __restrict__ stc,
                            const float* __restrict__ tcf,
                            float* __restrict__ convT) {
  int idx = blockIdx.x * 256 + threadIdx.x;
  if (idx >= NSTEP * NC) return;
  int t = idx / NC, c = idx - t * NC;
  float a = 0.f;
  for (int f = 0; f < NBF; ++f)
    a += stc[t + f] * tcf[c * NBF + f];
  convT[idx] = a;
}

// --- packed, time-reversed, edge-paired filter table (R=8 layout) ----------
// Per-cell stream: pair p<10 -> (cf[c][2p][99-i], cf[c][2p+1][99-i]);
// p==10 -> (ff[c][99-i], 0). Tap-block k = i>>2.
//   k < 14 (taps 0..55):   phys = p*14 + k             (stream-major)
//   k >= 14 (taps 56..99): phys = 154 + (k-14)*11 + p  (block-major)
// uint4 address: ((c>>2)*275 + phys)*4 + (c&3)  (4-cell interleave).
__global__ void pack_kernel(const float* __restrict__ cf,
                            const float* __restrict__ ff,
                            u32* __restrict__ wPT) {
  int idx = blockIdx.x * 256 + threadIdx.x;
  if (idx >= NC * 1100) return;
  int c = idx / 1100;
  int r = idx - c * 1100;
  int p = r / 100;
  int i = r - p * 100;
  int f = 99 - i;
  float lo, hi;
  if (p < 10) {
    lo = cf[(c * MC + 2 * p) * NBF + f];
    hi = cf[(c * MC + 2 * p + 1) * NBF + f];
  } else {
    lo = ff[c * NBF + f];
    hi = 0.f;
  }
  const int k = i >> 2;
  const int phys = (k < 14) ? (p * 14 + k) : (154 + (k - 14) * 11 + p);
  wPT[((((c >> 2) * 275 + phys) * 4 + (c & 3)) << 2) + (i & 3)] = pkrtz(lo, hi);
}

// --- head table: head[d][s][c] = packed tap-d weights (d=0..6) -------------
__global__ void head_kernel(const float* __restrict__ cf,
                            const float* __restrict__ ff,
                            u32* __restrict__ head) {
  int idx = blockIdx.x * 256 + threadIdx.x;
  if (idx >= 7 * 11 * NC) return;
  int c = idx % NC;
  int r = idx / NC;
  int s = r % 11;
  int d = r / 11;
  int f = 99 - d;
  float lo, hi;
  if (s < 10) {
    lo = cf[(c * MC + 2 * s) * NBF + f];
    hi = cf[(c * MC + 2 * s + 1) * NBF + f];
  } else {
    lo = ff[c * NBF + f];
    hi = 0.f;
  }
  head[(d * 11 + s) * NC + c] = pkrtz(lo, hi);
}

// --- packed source pairs, 11 rows: row 10 = (c, c) for feedback ------------
__global__ void selp_kernel(const int* __restrict__ sel, u32* __restrict__ selpT) {
  int idx = blockIdx.x * 256 + threadIdx.x;
  if (idx >= NC * 11) return;
  int c = idx % NC, p = idx / NC;
  u32 v;
  if (p < 10) {
    u32 s0 = (u32)sel[c * MC + 2 * p];
    u32 s1 = (u32)sel[c * MC + 2 * p + 1];
    v = s0 | (s1 << 16);
  } else {
    v = (u32)c | ((u32)c << 16);
  }
  selpT[p * NC + c] = v;
}

// --- initT2[b][tau][c] = init[b][c][tau]  (coalesced per-step reads) -------
__global__ void initT2_kernel(const float* __restrict__ init,
                              float* __restrict__ initT2) {
  int idx = blockIdx.x * 256 + threadIdx.x;
  if (idx >= NBATCH * NBI * NC) return;
  int c = idx % NC;
  int r = idx / NC;
  int tau = r % NBI;
  int b = r / NBI;
  initT2[idx] = init[(b * NC + c) * NBI + tau];
}

// --- copy initial spikes into output (first 100 bins of each row) ----------
__global__ void copy_init_kernel(const float4* __restrict__ init,
                                 float4* __restrict__ out) {
  int idx = blockIdx.x * 256 + threadIdx.x;
  if (idx >= NBATCH * NC * (NBI / 4)) return;
  int k4 = idx % (NBI / 4);
  int bc = idx / (NBI / 4);
  out[bc * (NB / 4) + k4] = init[idx];
}

// 8 dot2: one weight word WX times sources F0..F7 into acc[BASE..BASE+7]
#define ROW8(BASE, WX)                                                        \
  acc[(BASE)+0]=dot2(WX,F0,acc[(BASE)+0]); acc[(BASE)+1]=dot2(WX,F1,acc[(BASE)+1]); \
  acc[(BASE)+2]=dot2(WX,F2,acc[(BASE)+2]); acc[(BASE)+3]=dot2(WX,F3,acc[(BASE)+3]); \
  acc[(BASE)+4]=dot2(WX,F4,acc[(BASE)+4]); acc[(BASE)+5]=dot2(WX,F5,acc[(BASE)+5]); \
  acc[(BASE)+6]=dot2(WX,F6,acc[(BASE)+6]); acc[(BASE)+7]=dot2(WX,F7,acc[(BASE)+7]);

// full near block KB (2..11): dests acc[4KB-7 .. 4KB+3]
#define NB32(KB)                                                              \
  { const uint4 w = wn[(KB) * 4];                                             \
    ROW8(4*(KB)-7, w.x) ROW8(4*(KB)-6, w.y)                                   \
    ROW8(4*(KB)-5, w.z) ROW8(4*(KB)-4, w.w) }

// far: one weight word times fa[S][0..7] into 8 named ring temps
#define FD8(WX, S, E0,E1,E2,E3,E4,E5,E6,E7)                                   \
  E0=dot2(WX,fa[S][0],E0); E1=dot2(WX,fa[S][1],E1);                           \
  E2=dot2(WX,fa[S][2],E2); E3=dot2(WX,fa[S][3],E3);                           \
  E4=dot2(WX,fa[S][4],E4); E5=dot2(WX,fa[S][5],E5);                           \
  E6=dot2(WX,fa[S][6],E6); E7=dot2(WX,fa[S][7],E7);

#define FST(S)                                                                \
  { const uint4 w = wf[(S) * 4];                                              \
    FD8(w.x, S, d0,d1,d2,d3,d4,d5,d6,d7)                                      \
    FD8(w.y, S, d1,d2,d3,d4,d5,d6,d7,d8)                                      \
    FD8(w.z, S, d2,d3,d4,d5,d6,d7,d8,d9)                                      \
    FD8(w.w, S, d3,d4,d5,d6,d7,d8,d9,d10) }

// far pass over streams SB..SB+NS-1, blocks k=14..24, 11-slot ring RMW
#define FARPASS(SB, NS, CALLS)                                                \
  {                                                                           \
    u32 fa[4][8];                                                             \
    _Pragma("unroll")                                                         \
    for (int s = 0; s < (NS); ++s) {                                          \
      const u32 s01 = selpT[((SB) + s) * NC + c];                             \
      const int lo = (int)(s01 & 0xffffu), hi = (int)(s01 >> 16);             \
      _Pragma("unroll")                                                       \
      for (int m = 0; m < 8; ++m)                                             \
        fa[s][m] = (u32)spkh[m * NC + lo] | ((u32)spkh[m * NC + hi] << 16);   \
    }                                                                         \
    _Pragma("unroll 1")                                                       \
    for (int k = 14; k <= 24; ++k) {                                          \
      const int sb = G + 4 * k + 1 + c;                                       \
      const int a0=sb&63, a1=(sb+1)&63, a2=(sb+2)&63, a3=(sb+3)&63,           \
                a4=(sb+4)&63, a5=(sb+5)&63, a6=(sb+6)&63, a7=(sb+7)&63,       \
                a8=(sb+8)&63, a9=(sb+9)&63, a10=(sb+10)&63;                   \
      float d0=fr[a0],d1=fr[a1],d2=fr[a2],d3=fr[a3],d4=fr[a4],d5=fr[a5],      \
            d6=fr[a6],d7=fr[a7],d8=fr[a8],d9=fr[a9],d10=fr[a10];              \
      const uint4* __restrict__ wf = wc + (154 + (k - 14) * 11 + (SB)) * 4;   \
      CALLS                                                                   \
      fr[a0]=d0; fr[a1]=d1; fr[a2]=d2; fr[a3]=d3; fr[a4]=d4; fr[a5]=d5;       \
      fr[a6]=d6; fr[a7]=d7; fr[a8]=d8; fr[a9]=d9; fr[a10]=d10;                \
    }                                                                         \
  }

// head-scatter of source J into in-group dests acc[J+1 .. 7] (tap D=0..6-J)
#define HEADSC(J)                                                             \
  _Pragma("unroll")                                                           \
  for (int p = 0; p < 11; ++p) {                                              \
    const u32 s01 = selpT[p * NC + c];                                        \
    const int lo = (int)(s01 & 0xffffu), hi = (int)(s01 >> 16);               \
    const u32 pk = (u32)spkh[(J) * NC + lo] |                                 \
                   ((u32)spkh[(J) * NC + hi] << 16);                          \
    _Pragma("unroll")                                                         \
    for (int D = 0; D <= 6 - (J); ++D)                                        \
      acc[(J) + 1 + D] =                                                      \
          dot2(hd[(D * 11 + p) * NC + c], pk, acc[(J) + 1 + D]);              \
  }

#define SUB_GEN(J)                                                            \
  {                                                                           \
    const int t = G + (J) - NBI;                                              \
    float g = biasv + appv * convT[t * NC + c] + acc[J];                      \
    const float sv = 1.f / (1.f + __expf(-g));                                \
    outS[t] = sv;                                                             \
    outG[t] = g;                                                              \
    spkh[(J) * NC + c] = (unsigned short)pkrtz(sv, 0.f);                      \
    __syncthreads();                                                          \
    if ((J) < 7) { HEADSC(J) }                                                \
  }

#define SUB_INI(J)                                                            \
  {                                                                           \
    const float sv = ib2[(G + (J)) * NC + c];                                 \
    spkh[(J) * NC + c] = (unsigned short)pkrtz(sv, 0.f);                      \
    __syncthreads();                                                          \
    if ((J) < 7) { HEADSC(J) }                                                \
  }

// --- the recurrence: one wg per batch; R=8 group-batched scatter -----------
__global__ __attribute__((amdgpu_flat_work_group_size(NC, NC)))
void sim_kernel(
    const float* __restrict__ bias, const float* __restrict__ applied,
    const float* __restrict__ convT, const uint4* __restrict__ wp,
    const u32* __restrict__ selpT, const u32* __restrict__ hd,
    const float* __restrict__ initT2, float* __restrict__ out) {
  extern __shared__ char smem[];
  float* __restrict__ farb = (float*)smem;                        // [600][64]
  unsigned short* __restrict__ spkh =
      (unsigned short*)(smem + LDS_FAR_BYTES);                    // [8][600]

  const int c = threadIdx.x;     // cell, 0..599
  const int b = blockIdx.x;      // batch, 0..31
  float* __restrict__ fr = farb + c * 64;

#pragma unroll
  for (int s4 = 0; s4 < 16; ++s4)
    ((float4*)fr)[s4] = float4{0.f, 0.f, 0.f, 0.f};

  float acc[48];
#pragma unroll
  for (int i = 0; i < 48; ++i) acc[i] = 0.f;

  const float biasv = bias[c];
  const float appv  = applied[b * NC + c];
  const float* ib2  = initT2 + (size_t)b * NBI * NC;
  float* outS = out + (size_t)(b * NC + c) * NB + NBI;
  float* outG = out + (size_t)NBATCH * NC * NB + (size_t)(b * NC + c) * NSTEP;

  // single per-lane weight base (4-cell interleave): block phys at wc[phys*4]
  const uint4* __restrict__ wc = wp + ((c >> 2) * 1100 + (c & 3));

  __syncthreads();

#pragma unroll 1
  for (int G = 0; G < NB; G += 8) {
    // ---- 8 generation sub-steps (1 barrier each; head-scatter replaces
    //      the old CORR: source J's tap-(0..6-J) terms go into acc[J+1..7])
    if (G >= NBI) {
      SUB_GEN(0) SUB_GEN(1) SUB_GEN(2) SUB_GEN(3)
      if (G + 8 > NB) break;   // tail group G=496: steps 496..499 only
      SUB_GEN(4) SUB_GEN(5) SUB_GEN(6) SUB_GEN(7)
    } else if (G + 8 <= NBI) {
      SUB_INI(0) SUB_INI(1) SUB_INI(2) SUB_INI(3)
      SUB_INI(4) SUB_INI(5) SUB_INI(6) SUB_INI(7)
    } else {  // G == 96: steps 96..99 init, 100..103 gen
      SUB_INI(0) SUB_INI(1) SUB_INI(2) SUB_INI(3)
      SUB_GEN(4) SUB_GEN(5) SUB_GEN(6) SUB_GEN(7)
    }

    // ---- rotate window by 8 + ring handoff (dests G+48..G+55) ----
#pragma unroll
    for (int i = 0; i < 40; ++i) acc[i] = acc[i + 8];
#pragma unroll
    for (int r = 0; r < 8; ++r) {
      const int hs = (G + 48 + r + c) & 63;
      acc[40 + r] = fr[hs];
      fr[hs] = 0.f;
    }

    // ---- straddle ring temps: dests G'+48..G'+55 (G' = G+8) ----
    const int sb0 = G + 56 + c;
    float e0 = fr[(sb0 + 0) & 63], e1 = fr[(sb0 + 1) & 63];
    float e2 = fr[(sb0 + 2) & 63], e3 = fr[(sb0 + 3) & 63];
    float e4 = fr[(sb0 + 4) & 63], e5 = fr[(sb0 + 5) & 63];
    float e6 = fr[(sb0 + 6) & 63], e7 = fr[(sb0 + 7) & 63];

    // ---- near + straddle scatter: rolled over the 11 streams ----
#pragma unroll 1
    for (int p = 0; p < 11; ++p) {
      const u32 s01 = selpT[p * NC + c];
      const int lo = (int)(s01 & 0xffffu), hi = (int)(s01 >> 16);
      const u32 F0 = (u32)spkh[0*NC+lo] | ((u32)spkh[0*NC+hi] << 16);
      const u32 F1 = (u32)spkh[1*NC+lo] | ((u32)spkh[1*NC+hi] << 16);
      const u32 F2 = (u32)spkh[2*NC+lo] | ((u32)spkh[2*NC+hi] << 16);
      const u32 F3 = (u32)spkh[3*NC+lo] | ((u32)spkh[3*NC+hi] << 16);
      const u32 F4 = (u32)spkh[4*NC+lo] | ((u32)spkh[4*NC+hi] << 16);
      const u32 F5 = (u32)spkh[5*NC+lo] | ((u32)spkh[5*NC+hi] << 16);
      const u32 F6 = (u32)spkh[6*NC+lo] | ((u32)spkh[6*NC+hi] << 16);
      const u32 F7 = (u32)spkh[7*NC+lo] | ((u32)spkh[7*NC+hi] << 16);
      const uint4* __restrict__ wn = wc + p * 56;
      {  // triangular block 0 (taps 0..3): keep i+m>=7 only
        const uint4 w = wn[0];
        acc[0] = dot2(w.x, F7, acc[0]);
        acc[0] = dot2(w.y, F6, acc[0]); acc[1] = dot2(w.y, F7, acc[1]);
        acc[0] = dot2(w.z, F5, acc[0]); acc[1] = dot2(w.z, F6, acc[1]);
        acc[2] = dot2(w.z, F7, acc[2]);
        acc[0] = dot2(w.w, F4, acc[0]); acc[1] = dot2(w.w, F5, acc[1]);
        acc[2] = dot2(w.w, F6, acc[2]); acc[3] = dot2(w.w, F7, acc[3]);
      }
      {  // triangular block 1 (taps 4..7): keep i+m>=7 only
        const uint4 w = wn[4];
        acc[0] = dot2(w.x, F3, acc[0]); acc[1] = dot2(w.x, F4, acc[1]);
        acc[2] = dot2(w.x, F5, acc[2]); acc[3] = dot2(w.x, F6, acc[3]);
        acc[4] = dot2(w.x, F7, acc[4]);
        acc[0] = dot2(w.y, F2, acc[0]); acc[1] = dot2(w.y, F3, acc[1]);
        acc[2] = dot2(w.y, F4, acc[2]); acc[3] = dot2(w.y, F5, acc[3]);
        acc[4] = dot2(w.y, F6, acc[4]); acc[5] = dot2(w.y, F7, acc[5]);
        acc[0] = dot2(w.z, F1, acc[0]); acc[1] = dot2(w.z, F2, acc[1]);
        acc[2] = dot2(w.z, F3, acc[2]); acc[3] = dot2(w.z, F4, acc[3]);
        acc[4] = dot2(w.z, F5, acc[4]); acc[5] = dot2(w.z, F6, acc[5]);
        acc[6] = dot2(w.z, F7, acc[6]);
        ROW8(0, w.w)
      }
      NB32(2) NB32(3) NB32(4) NB32(5)
      __builtin_amdgcn_sched_barrier(0);
      NB32(6) NB32(7) NB32(8) NB32(9)
      __builtin_amdgcn_sched_barrier(0);
      NB32(10) NB32(11)
      {  // straddle block 12 (taps 48..51): acc[41..47] + e0..e3
        const uint4 w = wn[48];
        acc[41]=dot2(w.x,F0,acc[41]); acc[42]=dot2(w.x,F1,acc[42]);
        acc[43]=dot2(w.x,F2,acc[43]); acc[44]=dot2(w.x,F3,acc[44]);
        acc[45]=dot2(w.x,F4,acc[45]); acc[46]=dot2(w.x,F5,acc[46]);
        acc[47]=dot2(w.x,F6,acc[47]); e0=dot2(w.x,F7,e0);
        acc[42]=dot2(w.y,F0,acc[42]); acc[43]=dot2(w.y,F1,acc[43]);
        acc[44]=dot2(w.y,F2,acc[44]); acc[45]=dot2(w.y,F3,acc[45]);
        acc[46]=dot2(w.y,F4,acc[46]); acc[47]=dot2(w.y,F5,acc[47]);
        e0=dot2(w.y,F6,e0); e1=dot2(w.y,F7,e1);
        acc[43]=dot2(w.z,F0,acc[43]); acc[44]=dot2(w.z,F1,acc[44]);
        acc[45]=dot2(w.z,F2,acc[45]); acc[46]=dot2(w.z,F3,acc[46]);
        acc[47]=dot2(w.z,F4,acc[47]); e0=dot2(w.z,F5,e0);
        e1=dot2(w.z,F6,e1); e2=dot2(w.z,F7,e2);
        acc[44]=dot2(w.w,F0,acc[44]); acc[45]=dot2(w.w,F1,acc[45]);
        acc[46]=dot2(w.w,F2,acc[46]); acc[47]=dot2(w.w,F3,acc[47]);
        e0=dot2(w.w,F4,e0); e1=dot2(w.w,F5,e1);
        e2=dot2(w.w,F6,e2); e3=dot2(w.w,F7,e3);
      }
      {  // straddle block 13 (taps 52..55): acc[45..47] + e0..e7
        const uint4 w = wn[52];
        acc[45]=dot2(w.x,F0,acc[45]); acc[46]=dot2(w.x,F1,acc[46]);
        acc[47]=dot2(w.x,F2,acc[47]); e0=dot2(w.x,F3,e0);
        e1=dot2(w.x,F4,e1); e2=dot2(w.x,F5,e2);
        e3=dot2(w.x,F6,e3); e4=dot2(w.x,F7,e4);
        acc[46]=dot2(w.y,F0,acc[46]); acc[47]=dot2(w.y,F1,acc[47]);
        e0=dot2(w.y,F2,e0); e1=dot2(w.y,F3,e1);
        e2=dot2(w.y,F4,e2); e3=dot2(w.y,F5,e3);
        e4=dot2(w.y,F6,e4); e5=dot2(w.y,F7,e5);
        acc[47]=dot2(w.z,F0,acc[47]); e0=dot2(w.z,F1,e0);
        e1=dot2(w.z,F2,e1); e2=dot2(w.z,F3,e2);
        e3=dot2(w.z,F4,e3); e4=dot2(w.z,F5,e4);
        e5=dot2(w.z,F6,e5); e6=dot2(w.z,F7,e6);
        e0=dot2(w.w,F0,e0); e1=dot2(w.w,F1,e1);
        e2=dot2(w.w,F2,e2); e3=dot2(w.w,F3,e3);
        e4=dot2(w.w,F4,e4); e5=dot2(w.w,F5,e5);
        e6=dot2(w.w,F6,e6); e7=dot2(w.w,F7,e7);
      }
      __builtin_amdgcn_sched_barrier(0);
    }
    fr[(sb0 + 0) & 63] = e0; fr[(sb0 + 1) & 63] = e1;
    fr[(sb0 + 2) & 63] = e2; fr[(sb0 + 3) & 63] = e3;
    fr[(sb0 + 4) & 63] = e4; fr[(sb0 + 5) & 63] = e5;
    fr[(sb0 + 6) & 63] = e6; fr[(sb0 + 7) & 63] = e7;

    // ---- far scatter: 3 register-bounded passes over streams ----
    FARPASS(0, 4, FST(0) FST(1) FST(2) FST(3))
    FARPASS(4, 4, FST(0) FST(1) FST(2) FST(3))
    FARPASS(8, 3, FST(0) FST(1) FST(2))

    // close the group: no thread may write next group's spkh while another
    // still reads this group's spikes (WAR race latent since round 12)
    __syncthreads();
  }
}

extern "C" void kernel_launch(void* const* d_in, const int* in_sizes, int n_in,
                              void* d_out, int out_size, void* d_ws, size_t ws_size,
                              hipStream_t stream) {
  const float* stim = (const float*)d_in[0];   // 32x64x64
  const float* init = (const float*)d_in[1];   // 32x600x100
  const float* spat = (const float*)d_in[2];   // 600x4096
  const float* tcf  = (const float*)d_in[3];   // 600x100
  const float* ff   = (const float*)d_in[4];   // 600x100
  const float* cf   = (const float*)d_in[5];   // 600x20x100
  const float* bias = (const float*)d_in[6];   // 600x1
  const int*   sel  = (const int*)d_in[7];     // 600x20 int32
  const float* stc  = (const float*)d_in[8];   // 500
  float* out = (float*)d_out;                  // spikes 32x600x500, gensig 32x600x400

  char* ws = (char*)d_ws;
  float* applied = (float*)ws;                       //     76,800 B
  float* convT   = (float*)(ws + 76800);             //    960,000 B
  u32*   wPT     = (u32*)(ws + 1036800);             //  2,640,000 B
  u32*   selpT   = (u32*)(ws + 3676800);             //     26,400 B
  u32*   head    = (u32*)(ws + 3703200);             //    184,800 B
  float* initT2  = (float*)(ws + 3888000);           //  7,680,000 B (end ~11.6 MB)
  (void)ws_size; (void)in_sizes; (void)n_in; (void)out_size;

  static int lds_opted = 0;
  if (!lds_opted) {
    hipFuncSetAttribute((const void*)sim_kernel,
                        hipFuncAttributeMaxDynamicSharedMemorySize, LDS_TOTAL);
    lds_opted = 1;
  }

  hipLaunchKernelGGL(applied_kernel, dim3(NC, NBATCH), dim3(256), 0, stream,
                     stim, spat, applied);
  hipLaunchKernelGGL(conv_kernel, dim3((NSTEP * NC + 255) / 256), dim3(256), 0,
                     stream, stc, tcf, convT);
  hipLaunchKernelGGL(pack_kernel, dim3((NC * 1100 + 255) / 256), dim3(256), 0,
                     stream, cf, ff, wPT);
  hipLaunchKernelGGL(head_kernel, dim3((7 * 11 * NC + 255) / 256), dim3(256), 0,
                     stream, cf, ff, head);
  hipLaunchKernelGGL(selp_kernel, dim3((NC * 11 + 255) / 256), dim3(256), 0,
                     stream, sel, selpT);
  hipLaunchKernelGGL(initT2_kernel, dim3((NBATCH * NBI * NC + 255) / 256),
                     dim3(256), 0, stream, init, initT2);
  hipLaunchKernelGGL(copy_init_kernel,
                     dim3((NBATCH * NC * (NBI / 4) + 255) / 256), dim3(256), 0,
                     stream, (const float4*)init, (float4*)out);
  hipLaunchKernelGGL(sim_kernel, dim3(NBATCH), dim3(NC), LDS_TOTAL, stream,
                     bias, applied, convT, (const uint4*)wPT, selpT, head,
                     initT2, out);
}

// Round 10
// 7358.071 us; speedup vs baseline: 5.9261x; 1.3544x over previous
//
#include <hip/hip_runtime.h>

// ---------------------------------------------------------------------------
// NS_Flashed_TotalSimRetina — GLM retina simulation, round 15.
// Round 14 (tap-axis 2-stage pipeline) FAILED correctness from a workspace
// bug, not the algorithm: pbuf was carved as 614,400 BYTES but indexed as
// 614,400 u32 ELEMENTS (2,457,600 B). Batches b>=8 wrote partials past the
// region; batch 8 / window 0 / cells 0..7 landed exactly on cnt[0..63],
// turning the sync counters into float-bit garbage -> every poll passed
// instantly -> both roles free-ran on stale spikes (absmax 0.35, no hang).
// This round: identical kernel, fixed allocation (pbuf = 2,457,600 B; cnt
// moved to +33,379,200; total ~33.4 MB, under the >=42 MB workspace proven
// in round 5). Everything below the allocator is byte-identical to r14:
//   role 0: substeps + head-scatter + near taps 0..55 + 16-slot LDS
//           mini-ring straddle; publishes spikes; polls far partials.
//   role 1: far taps 56..99 (FARPASS blocks 14..24) on a 64-slot LDS ring,
//           lags 1 group, finalizes dests S+56..S+63 into 4-deep pbuf.
// ---------------------------------------------------------------------------

#define NC     600
#define NPIX   4096
#define NBF    100
#define MC     20
#define NB     500
#define NBI    100
#define NBATCH 32
#define NSTEP  400

#define LDS_FAR_BYTES (NC * 64 * 4)                 // 153,600 (role 1 ring)
#define LDS_TOTAL     (LDS_FAR_BYTES + 8 * NC * 2)  // 163,200

typedef unsigned int u32;
typedef _Float16 f16x2 __attribute__((ext_vector_type(2)));

__device__ __forceinline__ float dot2(u32 a, u32 b, float acc) {
  return __builtin_amdgcn_fdot2(__builtin_bit_cast(f16x2, a),
                                __builtin_bit_cast(f16x2, b), acc, false);
}
__device__ __forceinline__ u32 pkrtz(float a, float b) {
  return __builtin_bit_cast(u32, __builtin_amdgcn_cvt_pkrtz(a, b));
}
__device__ __forceinline__ u32 aload(const u32* p) {
  return __hip_atomic_load(p, __ATOMIC_RELAXED, __HIP_MEMORY_SCOPE_AGENT);
}
__device__ __forceinline__ void astore(u32* p, u32 v) {
  __hip_atomic_store(p, v, __ATOMIC_RELAXED, __HIP_MEMORY_SCOPE_AGENT);
}

// --- zero the sync counters ------------------------------------------------
__global__ void clear_kernel(u32* __restrict__ cnt) {
  int i = blockIdx.x * 256 + threadIdx.x;
  if (i < 2 * NBATCH) cnt[i] = 0u;
}

// --- stim_applied[b][c] = sum_p stim[b][p] * spat[c][p] ---------------------
__global__ void applied_kernel(const float* __restrict__ stim,
                               const float* __restrict__ spat,
                               float* __restrict__ applied) {
  const int c = blockIdx.x, b = blockIdx.y;
  __shared__ float red[256];
  float a = 0.f;
  for (int p = threadIdx.x; p < NPIX; p += 256)
    a += stim[b * NPIX + p] * spat[c * NPIX + p];
  red[threadIdx.x] = a;
  __syncthreads();
  for (int s = 128; s > 0; s >>= 1) {
    if (threadIdx.x < s) red[threadIdx.x] += red[threadIdx.x + s];
    __syncthreads();
  }
  if (threadIdx.x == 0) applied[b * NC + c] = red[0];
}

// --- convT[t][c] = sum_f stc[t+f] * tcf[c][f] ------------------------------
__global__ void conv_kernel(const float* __restrict__ stc,
                            const float* __restrict__ tcf,
                            float* __restrict__ convT) {
  int idx = blockIdx.x * 256 + threadIdx.x;
  if (idx >= NSTEP * NC) return;
  int t = idx / NC, c = idx - t * NC;
  float a = 0.f;
  for (int f = 0; f < NBF; ++f)
    a += stc[t + f] * tcf[c * NBF + f];
  convT[idx] = a;
}

// --- packed, time-reversed, edge-paired filter table (round-13 layout) -----
//   k < 14 (taps 0..55):   phys = p*14 + k             (stream-major, role 0)
//   k >= 14 (taps 56..99): phys = 154 + (k-14)*11 + p  (block-major, role 1)
// uint4 address: ((c>>2)*275 + phys)*4 + (c&3)  (4-cell interleave).
__global__ void pack_kernel(const float* __restrict__ cf,
                            const float* __restrict__ ff,
                            u32* __restrict__ wPT) {
  int idx = blockIdx.x * 256 + threadIdx.x;
  if (idx >= NC * 1100) return;
  int c = idx / 1100;
  int r = idx - c * 1100;
  int p = r / 100;
  int i = r - p * 100;
  int f = 99 - i;
  float lo, hi;
  if (p < 10) {
    lo = cf[(c * MC + 2 * p) * NBF + f];
    hi = cf[(c * MC + 2 * p + 1) * NBF + f];
  } else {
    lo = ff[c * NBF + f];
    hi = 0.f;
  }
  const int k = i >> 2;
  const int phys = (k < 14) ? (p * 14 + k) : (154 + (k - 14) * 11 + p);
  wPT[((((c >> 2) * 275 + phys) * 4 + (c & 3)) << 2) + (i & 3)] = pkrtz(lo, hi);
}

// --- head table: head[d][s][c] = packed tap-d weights (d=0..6) -------------
__global__ void head_kernel(const float* __restrict__ cf,
                            const float* __restrict__ ff,
                            u32* __restrict__ head) {
  int idx = blockIdx.x * 256 + threadIdx.x;
  if (idx >= 7 * 11 * NC) return;
  int c = idx % NC;
  int r = idx / NC;
  int s = r % 11;
  int d = r / 11;
  int f = 99 - d;
  float lo, hi;
  if (s < 10) {
    lo = cf[(c * MC + 2 * s) * NBF + f];
    hi = cf[(c * MC + 2 * s + 1) * NBF + f];
  } else {
    lo = ff[c * NBF + f];
    hi = 0.f;
  }
  head[(d * 11 + s) * NC + c] = pkrtz(lo, hi);
}

// --- packed source pairs, 11 rows: row 10 = (c, c) for feedback ------------
__global__ void selp_kernel(const int* __restrict__ sel, u32* __restrict__ selpT) {
  int idx = blockIdx.x * 256 + threadIdx.x;
  if (idx >= NC * 11) return;
  int c = idx % NC, p = idx / NC;
  u32 v;
  if (p < 10) {
    u32 s0 = (u32)sel[c * MC + 2 * p];
    u32 s1 = (u32)sel[c * MC + 2 * p + 1];
    v = s0 | (s1 << 16);
  } else {
    v = (u32)c | ((u32)c << 16);
  }
  selpT[p * NC + c] = v;
}

// --- initT2[b][tau][c] = init[b][c][tau]  (coalesced per-step reads) -------
__global__ void initT2_kernel(const float* __restrict__ init,
                              float* __restrict__ initT2) {
  int idx = blockIdx.x * 256 + threadIdx.x;
  if (idx >= NBATCH * NBI * NC) return;
  int c = idx % NC;
  int r = idx / NC;
  int tau = r % NBI;
  int b = r / NBI;
  initT2[idx] = init[(b * NC + c) * NBI + tau];
}

// --- copy initial spikes into output (first 100 bins of each row) ----------
__global__ void copy_init_kernel(const float4* __restrict__ init,
                                 float4* __restrict__ out) {
  int idx = blockIdx.x * 256 + threadIdx.x;
  if (idx >= NBATCH * NC * (NBI / 4)) return;
  int k4 = idx % (NBI / 4);
  int bc = idx / (NBI / 4);
  out[bc * (NB / 4) + k4] = init[idx];
}

// 8 dot2: one weight word WX times sources F0..F7 into acc[BASE..BASE+7]
#define ROW8(BASE, WX)                                                        \
  acc[(BASE)+0]=dot2(WX,F0,acc[(BASE)+0]); acc[(BASE)+1]=dot2(WX,F1,acc[(BASE)+1]); \
  acc[(BASE)+2]=dot2(WX,F2,acc[(BASE)+2]); acc[(BASE)+3]=dot2(WX,F3,acc[(BASE)+3]); \
  acc[(BASE)+4]=dot2(WX,F4,acc[(BASE)+4]); acc[(BASE)+5]=dot2(WX,F5,acc[(BASE)+5]); \
  acc[(BASE)+6]=dot2(WX,F6,acc[(BASE)+6]); acc[(BASE)+7]=dot2(WX,F7,acc[(BASE)+7]);

// full near block KB (2..11): dests acc[4KB-7 .. 4KB+3]
#define NB32(KB)                                                              \
  { const uint4 w = wn[(KB) * 4];                                             \
    ROW8(4*(KB)-7, w.x) ROW8(4*(KB)-6, w.y)                                   \
    ROW8(4*(KB)-5, w.z) ROW8(4*(KB)-4, w.w) }

// far: one weight word times fa[S][0..7] into 8 named ring temps
#define FD8(WX, S, E0,E1,E2,E3,E4,E5,E6,E7)                                   \
  E0=dot2(WX,fa[S][0],E0); E1=dot2(WX,fa[S][1],E1);                           \
  E2=dot2(WX,fa[S][2],E2); E3=dot2(WX,fa[S][3],E3);                           \
  E4=dot2(WX,fa[S][4],E4); E5=dot2(WX,fa[S][5],E5);                           \
  E6=dot2(WX,fa[S][6],E6); E7=dot2(WX,fa[S][7],E7);

#define FST(S)                                                                \
  { const uint4 w = wf[(S) * 4];                                              \
    FD8(w.x, S, d0,d1,d2,d3,d4,d5,d6,d7)                                      \
    FD8(w.y, S, d1,d2,d3,d4,d5,d6,d7,d8)                                      \
    FD8(w.z, S, d2,d3,d4,d5,d6,d7,d8,d9)                                      \
    FD8(w.w, S, d3,d4,d5,d6,d7,d8,d9,d10) }

// far pass over streams SB..SB+NS-1, blocks k=14..24, 11-slot ring RMW
#define FARPASS(SB, NS, CALLS)                                                \
  {                                                                           \
    u32 fa[4][8];                                                             \
    _Pragma("unroll")                                                         \
    for (int s = 0; s < (NS); ++s) {                                          \
      const u32 s01 = selpT[((SB) + s) * NC + c];                             \
      const int lo = (int)(s01 & 0xffffu), hi = (int)(s01 >> 16);             \
      _Pragma("unroll")                                                       \
      for (int m = 0; m < 8; ++m)                                             \
        fa[s][m] = (u32)spkh[m * NC + lo] | ((u32)spkh[m * NC + hi] << 16);   \
    }                                                                         \
    _Pragma("unroll 1")                                                       \
    for (int k = 14; k <= 24; ++k) {                                          \
      const int sb = S0 + 4 * k + 1 + c;                                      \
      const int a0=sb&63, a1=(sb+1)&63, a2=(sb+2)&63, a3=(sb+3)&63,           \
                a4=(sb+4)&63, a5=(sb+5)&63, a6=(sb+6)&63, a7=(sb+7)&63,       \
                a8=(sb+8)&63, a9=(sb+9)&63, a10=(sb+10)&63;                   \
      float d0=fr[a0],d1=fr[a1],d2=fr[a2],d3=fr[a3],d4=fr[a4],d5=fr[a5],      \
            d6=fr[a6],d7=fr[a7],d8=fr[a8],d9=fr[a9],d10=fr[a10];              \
      const uint4* __restrict__ wf = wc + (154 + (k - 14) * 11 + (SB)) * 4;   \
      CALLS                                                                   \
      fr[a0]=d0; fr[a1]=d1; fr[a2]=d2; fr[a3]=d3; fr[a4]=d4; fr[a5]=d5;       \
      fr[a6]=d6; fr[a7]=d7; fr[a8]=d8; fr[a9]=d9; fr[a10]=d10;                \
    }                                                                         \
  }

// head-scatter of source J into in-group dests acc[J+1 .. 7] (tap D=0..6-J)
#define HEADSC(J)                                                             \
  _Pragma("unroll")                                                           \
  for (int p = 0; p < 11; ++p) {                                              \
    const u32 s01 = selpT[p * NC + c];                                        \
    const int lo = (int)(s01 & 0xffffu), hi = (int)(s01 >> 16);               \
    const u32 pk = (u32)spkh[(J) * NC + lo] |                                 \
                   ((u32)spkh[(J) * NC + hi] << 16);                          \
    _Pragma("unroll")                                                         \
    for (int D = 0; D <= 6 - (J); ++D)                                        \
      acc[(J) + 1 + D] =                                                      \
          dot2(hd[(D * 11 + p) * NC + c], pk, acc[(J) + 1 + D]);              \
  }

#define SUB_GEN(J)                                                            \
  {                                                                           \
    const int t = G + (J) - NBI;                                              \
    float g = biasv + appv * convT[t * NC + c] + acc[J];                      \
    const float sv = 1.f / (1.f + __expf(-g));                                \
    outS[t] = sv;                                                             \
    outG[t] = g;                                                              \
    spkh[(J) * NC + c] = (unsigned short)pkrtz(sv, 0.f);                      \
    __syncthreads();                                                          \
    if ((J) < 7) { HEADSC(J) }                                                \
  }

#define SUB_INI(J)                                                            \
  {                                                                           \
    const float sv = ib2[(G + (J)) * NC + c];                                 \
    spkh[(J) * NC + c] = (unsigned short)pkrtz(sv, 0.f);                      \
    __syncthreads();                                                          \
    if ((J) < 7) { HEADSC(J) }                                                \
  }

// --- the recurrence: 2 wgs per batch — role 0 (near+serial) / role 1 (far) -
__global__ __attribute__((amdgpu_flat_work_group_size(NC, NC)))
void sim_kernel(
    const float* __restrict__ bias, const float* __restrict__ applied,
    const float* __restrict__ convT, const uint4* __restrict__ wp,
    const u32* __restrict__ selpT, const u32* __restrict__ hd,
    const float* __restrict__ initT2, float* __restrict__ out,
    u32* __restrict__ gspk, u32* __restrict__ pbuf, u32* __restrict__ cnt) {
  extern __shared__ char smem[];
  const int tid  = threadIdx.x;
  const int role = blockIdx.x & 1;
  const int b    = blockIdx.x >> 1;
  const int c    = tid;

  // single per-lane weight base (4-cell interleave): block phys at wc[phys*4]
  const uint4* __restrict__ wc = wp + ((c >> 2) * 1100 + (c & 3));
  u32* cnt_spk = cnt + 2 * b;       // spikes published through group g0 (=g0+1)
  u32* cnt_far = cnt + 2 * b + 1;   // far windows finalized through g1 (=g1+1)
  const int j0 = (c >= 300) ? 4 : 0;
  const int cc = (c >= 300) ? c - 300 : c;

  if (role == 0) {
    // ---------------- role 0: substeps + head + near taps 0..55 -----------
    float* __restrict__ fr16 = (float*)smem + c * 16;           // [600][16]
    unsigned short* __restrict__ spkh =
        (unsigned short*)(smem + NC * 16 * 4);                  // [8][600]

#pragma unroll
    for (int s4 = 0; s4 < 4; ++s4)
      ((float4*)fr16)[s4] = float4{0.f, 0.f, 0.f, 0.f};

    float acc[48];
#pragma unroll
    for (int i = 0; i < 48; ++i) acc[i] = 0.f;

    const float biasv = bias[c];
    const float appv  = applied[b * NC + c];
    const float* ib2  = initT2 + (size_t)b * NBI * NC;
    float* outS = out + (size_t)(b * NC + c) * NB + NBI;
    float* outG = out + (size_t)NBATCH * NC * NB + (size_t)(b * NC + c) * NSTEP;

    __syncthreads();

#pragma unroll 1
    for (int G = 0; G < NB; G += 8) {
      const int g0 = G >> 3;
      // ---- 8 generation sub-steps (1 barrier each) ----
      if (G >= NBI) {
        SUB_GEN(0) SUB_GEN(1) SUB_GEN(2) SUB_GEN(3)
        if (G + 8 > NB) break;   // tail group G=496: steps 496..499 only
        SUB_GEN(4) SUB_GEN(5) SUB_GEN(6) SUB_GEN(7)
      } else if (G + 8 <= NBI) {
        SUB_INI(0) SUB_INI(1) SUB_INI(2) SUB_INI(3)
        SUB_INI(4) SUB_INI(5) SUB_INI(6) SUB_INI(7)
      } else {  // G == 96: steps 96..99 init, 100..103 gen
        SUB_INI(0) SUB_INI(1) SUB_INI(2) SUB_INI(3)
        SUB_GEN(4) SUB_GEN(5) SUB_GEN(6) SUB_GEN(7)
      }

      // ---- publish this group's spikes (agent-scope -> MALL) ----
      {
        const u32* sp32 = (const u32*)spkh;
        u32* gp = gspk + (size_t)(b * 63 + g0) * 8 * 300;
#pragma unroll
        for (int jj = 0; jj < 4; ++jj)
          astore(&gp[(j0 + jj) * 300 + cc], sp32[(j0 + jj) * 300 + cc]);
        __syncthreads();            // drains vmcnt: all stores at MALL
        if (tid == 0) astore(cnt_spk, (u32)(g0 + 1));
      }

      // ---- rotate window by 8 ----
#pragma unroll
      for (int i = 0; i < 40; ++i) acc[i] = acc[i + 8];

      // ---- poll far partials for dests G+48..G+55 (window g0-1) ----
      float pr[8];
      if (g0 >= 1 && g0 <= 56) {
        if (tid == 0) {
          while (aload(cnt_far) < (u32)g0) __builtin_amdgcn_s_sleep(2);
        }
        __syncthreads();
        const u32* pb =
            pbuf + ((size_t)(b * 4 + ((g0 - 1) & 3)) * 600 + c) * 8;
#pragma unroll
        for (int r = 0; r < 8; ++r)
          pr[r] = __builtin_bit_cast(float, aload(&pb[r]));
      } else {
#pragma unroll
        for (int r = 0; r < 8; ++r) pr[r] = 0.f;
      }

      // ---- handoff: mini-ring (taps 48..55 history) + far partials ----
#pragma unroll
      for (int r = 0; r < 8; ++r) {
        const int hs = (G + 48 + r + c) & 15;
        acc[40 + r] = fr16[hs] + pr[r];
        fr16[hs] = 0.f;
      }

      // ---- straddle ring temps: dests G'+48..G'+55 (zero-seeded; far part
      //      arrives via pr at the next handoff) ----
      const int sb0 = G + 56 + c;
      float e0 = 0.f, e1 = 0.f, e2 = 0.f, e3 = 0.f;
      float e4 = 0.f, e5 = 0.f, e6 = 0.f, e7 = 0.f;

      // ---- near + straddle scatter: rolled over the 11 streams ----
#pragma unroll 1
      for (int p = 0; p < 11; ++p) {
        const u32 s01 = selpT[p * NC + c];
        const int lo = (int)(s01 & 0xffffu), hi = (int)(s01 >> 16);
        const u32 F0 = (u32)spkh[0*NC+lo] | ((u32)spkh[0*NC+hi] << 16);
        const u32 F1 = (u32)spkh[1*NC+lo] | ((u32)spkh[1*NC+hi] << 16);
        const u32 F2 = (u32)spkh[2*NC+lo] | ((u32)spkh[2*NC+hi] << 16);
        const u32 F3 = (u32)spkh[3*NC+lo] | ((u32)spkh[3*NC+hi] << 16);
        const u32 F4 = (u32)spkh[4*NC+lo] | ((u32)spkh[4*NC+hi] << 16);
        const u32 F5 = (u32)spkh[5*NC+lo] | ((u32)spkh[5*NC+hi] << 16);
        const u32 F6 = (u32)spkh[6*NC+lo] | ((u32)spkh[6*NC+hi] << 16);
        const u32 F7 = (u32)spkh[7*NC+lo] | ((u32)spkh[7*NC+hi] << 16);
        const uint4* __restrict__ wn = wc + p * 56;
        {  // triangular block 0 (taps 0..3): keep i+m>=7 only
          const uint4 w = wn[0];
          acc[0] = dot2(w.x, F7, acc[0]);
          acc[0] = dot2(w.y, F6, acc[0]); acc[1] = dot2(w.y, F7, acc[1]);
          acc[0] = dot2(w.z, F5, acc[0]); acc[1] = dot2(w.z, F6, acc[1]);
          acc[2] = dot2(w.z, F7, acc[2]);
          acc[0] = dot2(w.w, F4, acc[0]); acc[1] = dot2(w.w, F5, acc[1]);
          acc[2] = dot2(w.w, F6, acc[2]); acc[3] = dot2(w.w, F7, acc[3]);
        }
        {  // triangular block 1 (taps 4..7): keep i+m>=7 only
          const uint4 w = wn[4];
          acc[0] = dot2(w.x, F3, acc[0]); acc[1] = dot2(w.x, F4, acc[1]);
          acc[2] = dot2(w.x, F5, acc[2]); acc[3] = dot2(w.x, F6, acc[3]);
          acc[4] = dot2(w.x, F7, acc[4]);
          acc[0] = dot2(w.y, F2, acc[0]); acc[1] = dot2(w.y, F3, acc[1]);
          acc[2] = dot2(w.y, F4, acc[2]); acc[3] = dot2(w.y, F5, acc[3]);
          acc[4] = dot2(w.y, F6, acc[4]); acc[5] = dot2(w.y, F7, acc[5]);
          acc[0] = dot2(w.z, F1, acc[0]); acc[1] = dot2(w.z, F2, acc[1]);
          acc[2] = dot2(w.z, F3, acc[2]); acc[3] = dot2(w.z, F4, acc[3]);
          acc[4] = dot2(w.z, F5, acc[4]); acc[5] = dot2(w.z, F6, acc[5]);
          acc[6] = dot2(w.z, F7, acc[6]);
          ROW8(0, w.w)
        }
        NB32(2) NB32(3) NB32(4) NB32(5)
        __builtin_amdgcn_sched_barrier(0);
        NB32(6) NB32(7) NB32(8) NB32(9)
        __builtin_amdgcn_sched_barrier(0);
        NB32(10) NB32(11)
        {  // straddle block 12 (taps 48..51): acc[41..47] + e0..e3
          const uint4 w = wn[48];
          acc[41]=dot2(w.x,F0,acc[41]); acc[42]=dot2(w.x,F1,acc[42]);
          acc[43]=dot2(w.x,F2,acc[43]); acc[44]=dot2(w.x,F3,acc[44]);
          acc[45]=dot2(w.x,F4,acc[45]); acc[46]=dot2(w.x,F5,acc[46]);
          acc[47]=dot2(w.x,F6,acc[47]); e0=dot2(w.x,F7,e0);
          acc[42]=dot2(w.y,F0,acc[42]); acc[43]=dot2(w.y,F1,acc[43]);
          acc[44]=dot2(w.y,F2,acc[44]); acc[45]=dot2(w.y,F3,acc[45]);
          acc[46]=dot2(w.y,F4,acc[46]); acc[47]=dot2(w.y,F5,acc[47]);
          e0=dot2(w.y,F6,e0); e1=dot2(w.y,F7,e1);
          acc[43]=dot2(w.z,F0,acc[43]); acc[44]=dot2(w.z,F1,acc[44]);
          acc[45]=dot2(w.z,F2,acc[45]); acc[46]=dot2(w.z,F3,acc[46]);
          acc[47]=dot2(w.z,F4,acc[47]); e0=dot2(w.z,F5,e0);
          e1=dot2(w.z,F6,e1); e2=dot2(w.z,F7,e2);
          acc[44]=dot2(w.w,F0,acc[44]); acc[45]=dot2(w.w,F1,acc[45]);
          acc[46]=dot2(w.w,F2,acc[46]); acc[47]=dot2(w.w,F3,acc[47]);
          e0=dot2(w.w,F4,e0); e1=dot2(w.w,F5,e1);
          e2=dot2(w.w,F6,e2); e3=dot2(w.w,F7,e3);
        }
        {  // straddle block 13 (taps 52..55): acc[45..47] + e0..e7
          const uint4 w = wn[52];
          acc[45]=dot2(w.x,F0,acc[45]); acc[46]=dot2(w.x,F1,acc[46]);
          acc[47]=dot2(w.x,F2,acc[47]); e0=dot2(w.x,F3,e0);
          e1=dot2(w.x,F4,e1); e2=dot2(w.x,F5,e2);
          e3=dot2(w.x,F6,e3); e4=dot2(w.x,F7,e4);
          acc[46]=dot2(w.y,F0,acc[46]); acc[47]=dot2(w.y,F1,acc[47]);
          e0=dot2(w.y,F2,e0); e1=dot2(w.y,F3,e1);
          e2=dot2(w.y,F4,e2); e3=dot2(w.y,F5,e3);
          e4=dot2(w.y,F6,e4); e5=dot2(w.y,F7,e5);
          acc[47]=dot2(w.z,F0,acc[47]); e0=dot2(w.z,F1,e0);
          e1=dot2(w.z,F2,e1); e2=dot2(w.z,F3,e2);
          e3=dot2(w.z,F4,e3); e4=dot2(w.z,F5,e4);
          e5=dot2(w.z,F6,e5); e6=dot2(w.z,F7,e6);
          e0=dot2(w.w,F0,e0); e1=dot2(w.w,F1,e1);
          e2=dot2(w.w,F2,e2); e3=dot2(w.w,F3,e3);
          e4=dot2(w.w,F4,e4); e5=dot2(w.w,F5,e5);
          e6=dot2(w.w,F6,e6); e7=dot2(w.w,F7,e7);
        }
        __builtin_amdgcn_sched_barrier(0);
      }
      fr16[(sb0 + 0) & 15] = e0; fr16[(sb0 + 1) & 15] = e1;
      fr16[(sb0 + 2) & 15] = e2; fr16[(sb0 + 3) & 15] = e3;
      fr16[(sb0 + 4) & 15] = e4; fr16[(sb0 + 5) & 15] = e5;
      fr16[(sb0 + 6) & 15] = e6; fr16[(sb0 + 7) & 15] = e7;

      // close the group: no thread may write next group's spkh while another
      // still reads this group's spikes
      __syncthreads();
    }
  } else {
    // ---------------- role 1: far taps 56..99 on 64-slot ring --------------
    float* __restrict__ fr = (float*)smem + c * 64;             // [600][64]
    unsigned short* __restrict__ spkh =
        (unsigned short*)(smem + LDS_FAR_BYTES);                // [8][600]

#pragma unroll
    for (int s4 = 0; s4 < 16; ++s4)
      ((float4*)fr)[s4] = float4{0.f, 0.f, 0.f, 0.f};
    __syncthreads();

#pragma unroll 1
    for (int g1 = 0; g1 < 56; ++g1) {
      const int S0 = g1 * 8;
      // wait for spike group g1, then copy it into LDS
      if (tid == 0) {
        while (aload(cnt_spk) < (u32)(g1 + 1)) __builtin_amdgcn_s_sleep(2);
      }
      __syncthreads();
      {
        const u32* gp = gspk + (size_t)(b * 63 + g1) * 8 * 300;
        u32* sp32 = (u32*)spkh;
#pragma unroll
        for (int jj = 0; jj < 4; ++jj)
          sp32[(j0 + jj) * 300 + cc] = aload(&gp[(j0 + jj) * 300 + cc]);
      }
      __syncthreads();

      // far scatter: 3 register-bounded passes over streams
      FARPASS(0, 4, FST(0) FST(1) FST(2) FST(3))
      FARPASS(4, 4, FST(0) FST(1) FST(2) FST(3))
      FARPASS(8, 3, FST(0) FST(1) FST(2))

      // finalize dests S0+56..S0+63 -> partial window g1, zero slots
      {
        u32* pb = pbuf + ((size_t)(b * 4 + (g1 & 3)) * 600 + c) * 8;
#pragma unroll
        for (int r = 0; r < 8; ++r) {
          const int sl = (S0 + 56 + r + c) & 63;
          astore(&pb[r], __builtin_bit_cast(u32, fr[sl]));
          fr[sl] = 0.f;
        }
      }
      __syncthreads();            // drains vmcnt: partials at MALL
      if (tid == 0) astore(cnt_far, (u32)(g1 + 1));
    }
  }
}

extern "C" void kernel_launch(void* const* d_in, const int* in_sizes, int n_in,
                              void* d_out, int out_size, void* d_ws, size_t ws_size,
                              hipStream_t stream) {
  const float* stim = (const float*)d_in[0];   // 32x64x64
  const float* init = (const float*)d_in[1];   // 32x600x100
  const float* spat = (const float*)d_in[2];   // 600x4096
  const float* tcf  = (const float*)d_in[3];   // 600x100
  const float* ff   = (const float*)d_in[4];   // 600x100
  const float* cf   = (const float*)d_in[5];   // 600x20x100
  const float* bias = (const float*)d_in[6];   // 600x1
  const int*   sel  = (const int*)d_in[7];     // 600x20 int32
  const float* stc  = (const float*)d_in[8];   // 500
  float* out = (float*)d_out;                  // spikes 32x600x500, gensig 32x600x400

  char* ws = (char*)d_ws;
  float* applied = (float*)ws;                       //     76,800 B
  float* convT   = (float*)(ws + 76800);             //    960,000 B
  u32*   wPT     = (u32*)(ws + 1036800);             //  2,640,000 B
  u32*   selpT   = (u32*)(ws + 3676800);             //     26,400 B
  u32*   head    = (u32*)(ws + 3703200);             //    184,800 B
  float* initT2  = (float*)(ws + 3888000);           //  7,680,000 B
  u32*   gspk    = (u32*)(ws + 11568000);            // 19,353,600 B
  u32*   pbuf    = (u32*)(ws + 30921600);            //  2,457,600 B  (32*4*600*8 u32 — r14 sized this as 614,400 B and clobbered cnt)
  u32*   cnt     = (u32*)(ws + 33379200);            //        256 B  (end ~33.4 MB)
  (void)ws_size; (void)in_sizes; (void)n_in; (void)out_size;

  static int lds_opted = 0;
  if (!lds_opted) {
    hipFuncSetAttribute((const void*)sim_kernel,
                        hipFuncAttributeMaxDynamicSharedMemorySize, LDS_TOTAL);
    lds_opted = 1;
  }

  hipLaunchKernelGGL(clear_kernel, dim3(1), dim3(256), 0, stream, cnt);
  hipLaunchKernelGGL(applied_kernel, dim3(NC, NBATCH), dim3(256), 0, stream,
                     stim, spat, applied);
  hipLaunchKernelGGL(conv_kernel, dim3((NSTEP * NC + 255) / 256), dim3(256), 0,
                     stream, stc, tcf, convT);
  hipLaunchKernelGGL(pack_kernel, dim3((NC * 1100 + 255) / 256), dim3(256), 0,
                     stream, cf, ff, wPT);
  hipLaunchKernelGGL(head_kernel, dim3((7 * 11 * NC + 255) / 256), dim3(256), 0,
                     stream, cf, ff, head);
  hipLaunchKernelGGL(selp_kernel, dim3((NC * 11 + 255) / 256), dim3(256), 0,
                     stream, sel, selpT);
  hipLaunchKernelGGL(initT2_kernel, dim3((NBATCH * NBI * NC + 255) / 256),
                     dim3(256), 0, stream, init, initT2);
  hipLaunchKernelGGL(copy_init_kernel,
                     dim3((NBATCH * NC * (NBI / 4) + 255) / 256), dim3(256), 0,
                     stream, (const float4*)init, (float4*)out);
  hipLaunchKernelGGL(sim_kernel, dim3(2 * NBATCH), dim3(NC), LDS_TOTAL, stream,
                     bias, applied, convT, (const uint4*)wPT, selpT, head,
                     initT2, out, gspk, pbuf, cnt);
}